// Round 1
// baseline (2673.240 us; speedup 1.0000x reference)
//
#include <hip/hip_runtime.h>

#define BB 32
#define NN 512
#define FIN 74
#define DD 140
#define DF 128
#define LL 4
#define NEGV (-9e15f)

// ---------------------------------------------------------------------------
// embed: x[b,n,d] = sum_f c_hs[b,n,f] * We[d,f]
// 32 rows per block; We staged transposed in LDS.
__global__ __launch_bounds__(256) void k_embed(const float* __restrict__ chs,
                                               const float* __restrict__ We,
                                               float* __restrict__ x) {
    __shared__ float s_we[FIN * 144];     // [f][d] padded stride 144
    __shared__ float s_in[32 * FIN];
    int bn0 = blockIdx.x * 32;
    int tid = threadIdx.x;
    for (int idx = tid; idx < DD * FIN; idx += 256) {
        int r = idx / FIN, c = idx % FIN;           // r=d, c=f
        s_we[c * 144 + r] = We[idx];
    }
    for (int idx = tid; idx < 32 * FIN; idx += 256)
        s_in[idx] = chs[(size_t)bn0 * FIN + idx];
    __syncthreads();
    int d = tid;
    if (d < DD) {
        float acc[32];
#pragma unroll
        for (int r = 0; r < 32; ++r) acc[r] = 0.f;
        for (int f = 0; f < FIN; ++f) {
            float w = s_we[f * 144 + d];
#pragma unroll
            for (int r = 0; r < 32; ++r) acc[r] = fmaf(s_in[r * FIN + f], w, acc[r]);
        }
#pragma unroll
        for (int r = 0; r < 32; ++r) x[(size_t)(bn0 + r) * DD + d] = acc[r];
    }
}

// ---------------------------------------------------------------------------
// wtrans: h = x@Ww^T + Wb ; hA = h@A   (32 rows per block)
__global__ __launch_bounds__(256) void k_wtrans(const float* __restrict__ x,
                                                const float* __restrict__ Ww,
                                                const float* __restrict__ Wb,
                                                const float* __restrict__ A,
                                                float* __restrict__ h,
                                                float* __restrict__ hA) {
    __shared__ float s_x[32 * DD];
    __shared__ float s_h[32 * DD];
    __shared__ float s_w[32 * 144];     // transposed weight chunk [f][d]
    int bn0 = blockIdx.x * 32;
    int tid = threadIdx.x;
    for (int idx = tid; idx < 32 * DD; idx += 256) s_x[idx] = x[(size_t)bn0 * DD + idx];
    float acc[32];
#pragma unroll
    for (int r = 0; r < 32; ++r) acc[r] = 0.f;
    int d = tid;
    for (int f0 = 0; f0 < DD; f0 += 32) {
        int fn = (DD - f0) < 32 ? (DD - f0) : 32;
        __syncthreads();
        for (int idx = tid; idx < fn * DD; idx += 256) {
            int rr = idx / fn, cc = idx % fn;        // rr = d (weight row), cc = f offset
            s_w[cc * 144 + rr] = Ww[rr * DD + f0 + cc];
        }
        __syncthreads();
        if (d < DD) {
            for (int f = 0; f < fn; ++f) {
                float w = s_w[f * 144 + d];
#pragma unroll
                for (int r = 0; r < 32; ++r) acc[r] = fmaf(s_x[r * DD + f0 + f], w, acc[r]);
            }
        }
    }
    if (d < DD) {
        float bias = Wb[d];
#pragma unroll
        for (int r = 0; r < 32; ++r) {
            float v = acc[r] + bias;
            s_h[r * DD + d] = v;
            h[(size_t)(bn0 + r) * DD + d] = v;
            acc[r] = 0.f;
        }
    }
    __syncthreads();
    if (d < DD) {
        for (int dd2 = 0; dd2 < DD; ++dd2) {
            float a = A[dd2 * DD + d];               // coalesced across d
#pragma unroll
            for (int r = 0; r < 32; ++r) acc[r] = fmaf(s_h[r * DD + dd2], a, acc[r]);
        }
#pragma unroll
        for (int r = 0; r < 32; ++r) hA[(size_t)(bn0 + r) * DD + d] = acc[r];
    }
}

// ---------------------------------------------------------------------------
// esym: e[b,i,j] = hA[b,i]·h[b,j] + h[b,i]·hA[b,j]
// 32x32 tile per block; j-side in LDS (XOR-swizzled), i-side global broadcast.
#define ESTRIDE 160
__global__ __launch_bounds__(256) void k_esym(const float* __restrict__ h,
                                              const float* __restrict__ hA,
                                              float* __restrict__ e) {
    __shared__ __align__(16) float s_hj[32 * ESTRIDE];
    __shared__ __align__(16) float s_aj[32 * ESTRIDE];
    int b = blockIdx.z;
    int j0 = blockIdx.x * 32;
    int i0 = blockIdx.y * 32;
    const float* hb = h + (size_t)b * NN * DD;
    const float* ab = hA + (size_t)b * NN * DD;
    int tid = threadIdx.x;
    for (int idx = tid; idx < 32 * DD; idx += 256) {
        int r = idx / DD, c = idx % DD;
        int sw = r * ESTRIDE + ((((c >> 2) << 2)) ^ ((r & 7) << 2)) + (c & 3);
        s_hj[sw] = hb[(size_t)(j0 + r) * DD + c];
        s_aj[sw] = ab[(size_t)(j0 + r) * DD + c];
    }
    __syncthreads();
    int tx = tid & 15, ty = tid >> 4;
    float acc[2][2] = {{0.f, 0.f}, {0.f, 0.f}};
    for (int k = 0; k < DD; k += 4) {
        float4 ai[2], hi[2];
#pragma unroll
        for (int ri = 0; ri < 2; ++ri) {
            int i = i0 + ty + 16 * ri;
            ai[ri] = *reinterpret_cast<const float4*>(&ab[(size_t)i * DD + k]);
            hi[ri] = *reinterpret_cast<const float4*>(&hb[(size_t)i * DD + k]);
        }
#pragma unroll
        for (int rj = 0; rj < 2; ++rj) {
            int row = tx + 16 * rj;
            int sw = row * ESTRIDE + (k ^ ((row & 7) << 2));
            float4 hj = *reinterpret_cast<const float4*>(&s_hj[sw]);
            float4 aj = *reinterpret_cast<const float4*>(&s_aj[sw]);
#pragma unroll
            for (int ri = 0; ri < 2; ++ri) {
                acc[ri][rj] += ai[ri].x * hj.x + ai[ri].y * hj.y + ai[ri].z * hj.z + ai[ri].w * hj.w
                             + hi[ri].x * aj.x + hi[ri].y * aj.y + hi[ri].z * aj.z + hi[ri].w * aj.w;
            }
        }
    }
#pragma unroll
    for (int ri = 0; ri < 2; ++ri)
#pragma unroll
        for (int rj = 0; rj < 2; ++rj)
            e[(size_t)b * NN * NN + (size_t)(i0 + ty + 16 * ri) * NN + (j0 + tx + 16 * rj)] = acc[ri][rj];
}

// ---------------------------------------------------------------------------
// column-softmax stats over rows i (softmax axis=1) for BOTH adjacencies.
// cs outputs store RECIPROCAL of the denominator.
__global__ __launch_bounds__(256) void k_colsm(const float* __restrict__ e,
                                               const float* __restrict__ adj1,
                                               const float* __restrict__ dist,
                                               const float* __restrict__ mu_p,
                                               const float* __restrict__ dev_p,
                                               float* __restrict__ cm1, float* __restrict__ cs1,
                                               float* __restrict__ cm2, float* __restrict__ cs2) {
    int b = blockIdx.y;
    int j = blockIdx.x * 256 + threadIdx.x;
    float mu = mu_p[0], rdev = 1.0f / dev_p[0];
    size_t base = (size_t)b * NN * NN + j;
    float m1 = NEGV, s1 = 0.f, m2 = NEGV, s2 = 0.f;
    for (int i = 0; i < NN; ++i) {
        size_t off = base + (size_t)i * NN;
        float ev = e[off];
        float a1 = adj1[off];
        float dd = dist[off];
        float t = dd - mu;
        float a2 = __expf(-t * t * rdev) + a1;
        float v1 = a1 > 0.f ? ev : NEGV;
        float v2 = a2 > 0.f ? ev : NEGV;
        if (v1 > m1) { s1 = s1 * __expf(m1 - v1) + 1.f; m1 = v1; } else { s1 += __expf(v1 - m1); }
        if (v2 > m2) { s2 = s2 * __expf(m2 - v2) + 1.f; m2 = v2; } else { s2 += __expf(v2 - m2); }
    }
    cm1[b * NN + j] = m1; cs1[b * NN + j] = 1.0f / s1;
    cm2[b * NN + j] = m2; cs2[b * NN + j] = 1.0f / s2;
}

// ---------------------------------------------------------------------------
// hprime (both paths fused): hp[b,i,d] = relu( sum_j att[b,i,j]*h[b,j,d] )
// att rebuilt on the fly. 8 i-rows per block, j chunked by 64 with h staged.
__global__ __launch_bounds__(256) void k_hprime(const float* __restrict__ e,
                                                const float* __restrict__ adj1,
                                                const float* __restrict__ dist,
                                                const float* __restrict__ mu_p,
                                                const float* __restrict__ dev_p,
                                                const float* __restrict__ h,
                                                const float* __restrict__ cm1, const float* __restrict__ cs1,
                                                const float* __restrict__ cm2, const float* __restrict__ cs2,
                                                float* __restrict__ hp1, float* __restrict__ hp2) {
    __shared__ __align__(16) float s_h[64 * DD];
    __shared__ __align__(16) float s_a1[8 * 64];
    __shared__ __align__(16) float s_a2[8 * 64];
    int b = blockIdx.y;
    int i0 = blockIdx.x * 8;
    int tid = threadIdx.x;
    float mu = mu_p[0], rdev = 1.0f / dev_p[0];
    float acc1[8], acc2[8];
#pragma unroll
    for (int r = 0; r < 8; ++r) { acc1[r] = 0.f; acc2[r] = 0.f; }
    const float* hb = h + (size_t)b * NN * DD;
    int d = tid;
    for (int j0 = 0; j0 < NN; j0 += 64) {
        __syncthreads();
        for (int idx = tid; idx < 64 * DD; idx += 256) s_h[idx] = hb[(size_t)j0 * DD + idx];
#pragma unroll
        for (int p = 0; p < 2; ++p) {
            int pr = tid + p * 256;
            int r = pr >> 6, jj = pr & 63;
            int i = i0 + r, j = j0 + jj;
            size_t off = (size_t)b * NN * NN + (size_t)i * NN + j;
            float ev = e[off];
            float a1 = adj1[off];
            float ddv = dist[off];
            float t = ddv - mu;
            float a2 = __expf(-t * t * rdev) + a1;
            float e1 = fminf(ev - cm1[b * NN + j], 0.f);
            float e2 = fminf(ev - cm2[b * NN + j], 0.f);
            s_a1[r * 64 + jj] = a1 > 0.f ? a1 * __expf(e1) * cs1[b * NN + j] : 0.f;
            s_a2[r * 64 + jj] = a2 > 0.f ? a2 * __expf(e2) * cs2[b * NN + j] : 0.f;
        }
        __syncthreads();
        if (d < DD) {
            for (int jj = 0; jj < 64; jj += 4) {
                float hv0 = s_h[(jj + 0) * DD + d];
                float hv1 = s_h[(jj + 1) * DD + d];
                float hv2 = s_h[(jj + 2) * DD + d];
                float hv3 = s_h[(jj + 3) * DD + d];
#pragma unroll
                for (int r = 0; r < 8; ++r) {
                    float4 a1v = *reinterpret_cast<const float4*>(&s_a1[r * 64 + jj]);
                    float4 a2v = *reinterpret_cast<const float4*>(&s_a2[r * 64 + jj]);
                    acc1[r] += a1v.x * hv0 + a1v.y * hv1 + a1v.z * hv2 + a1v.w * hv3;
                    acc2[r] += a2v.x * hv0 + a2v.y * hv1 + a2v.z * hv2 + a2v.w * hv3;
                }
            }
        }
    }
    if (d < DD) {
#pragma unroll
        for (int r = 0; r < 8; ++r) {
            size_t o = (size_t)b * NN * DD + (size_t)(i0 + r) * DD + d;
            hp1[o] = fmaxf(acc1[r], 0.f);
            hp2[o] = fmaxf(acc2[r], 0.f);
        }
    }
}

// ---------------------------------------------------------------------------
// gate + layer update: x = gate(x,hp2) - gate(x,hp1)   (one wave per node)
__global__ __launch_bounds__(64) void k_gate(const float* __restrict__ hp1,
                                             const float* __restrict__ hp2,
                                             const float* __restrict__ gw,
                                             const float* __restrict__ gb,
                                             float* __restrict__ x) {
    int bn = blockIdx.x;
    int t = threadIdx.x;
    const float* xr = x + (size_t)bn * DD;
    const float* h1r = hp1 + (size_t)bn * DD;
    const float* h2r = hp2 + (size_t)bn * DD;
    float xv[3], h1v[3], h2v[3];
    float sx = 0.f, s1 = 0.f, s2 = 0.f;
#pragma unroll
    for (int q = 0; q < 3; ++q) {
        int dd2 = t + 64 * q;
        bool ok = dd2 < DD;
        xv[q]  = ok ? xr[dd2]  : 0.f;
        h1v[q] = ok ? h1r[dd2] : 0.f;
        h2v[q] = ok ? h2r[dd2] : 0.f;
        float gl = ok ? gw[dd2] : 0.f;
        float gh = ok ? gw[DD + dd2] : 0.f;
        sx = fmaf(xv[q], gl, sx);
        s1 = fmaf(h1v[q], gh, s1);
        s2 = fmaf(h2v[q], gh, s2);
    }
#pragma unroll
    for (int off = 32; off > 0; off >>= 1) {
        sx += __shfl_down(sx, off);
        s1 += __shfl_down(s1, off);
        s2 += __shfl_down(s2, off);
    }
    float z1 = __shfl(sx + s1, 0);
    float z2 = __shfl(sx + s2, 0);
    float gbv = gb[0];
    float c1 = 1.f / (1.f + __expf(-(z1 + gbv)));
    float c2 = 1.f / (1.f + __expf(-(z2 + gbv)));
#pragma unroll
    for (int q = 0; q < 3; ++q) {
        int dd2 = t + 64 * q;
        if (dd2 < DD) {
            float xnew = (c2 - c1) * xv[q] + (1.f - c2) * h2v[q] - (1.f - c1) * h1v[q];
            x[(size_t)bn * DD + dd2] = xnew;
        }
    }
}

// ---------------------------------------------------------------------------
// readout: g[b,d] = sum_n x[b,n,d] * valid[b,n]
__global__ __launch_bounds__(256) void k_readout(const float* __restrict__ x,
                                                 const float* __restrict__ valid,
                                                 float* __restrict__ g) {
    int b = blockIdx.x;
    int t = threadIdx.x;
    if (t < DD) {
        float acc = 0.f;
        for (int n = 0; n < NN; ++n)
            acc = fmaf(x[((size_t)b * NN + n) * DD + t], valid[b * NN + n], acc);
        g[b * DD + t] = acc;
    }
}

// ---------------------------------------------------------------------------
// tiny MLP head: relu x3 + sigmoid
__global__ __launch_bounds__(128) void k_mlp(const float* __restrict__ g,
                                             const float* __restrict__ w0, const float* __restrict__ b0,
                                             const float* __restrict__ w1, const float* __restrict__ b1,
                                             const float* __restrict__ w2, const float* __restrict__ b2,
                                             const float* __restrict__ w3, const float* __restrict__ b3,
                                             float* __restrict__ out) {
    __shared__ float s0[DD];
    __shared__ float s1[DF];
    __shared__ float s2[DF];
    __shared__ float s_part[2];
    int b = blockIdx.x, t = threadIdx.x;
    for (int i = t; i < DD; i += 128) s0[i] = g[b * DD + i];
    __syncthreads();
    float acc = b0[t];
    for (int dd2 = 0; dd2 < DD; ++dd2) acc = fmaf(s0[dd2], w0[dd2 * DF + t], acc);
    s1[t] = fmaxf(acc, 0.f);
    __syncthreads();
    acc = b1[t];
    for (int dd2 = 0; dd2 < DF; ++dd2) acc = fmaf(s1[dd2], w1[dd2 * DF + t], acc);
    s2[t] = fmaxf(acc, 0.f);
    __syncthreads();
    acc = b2[t];
    for (int dd2 = 0; dd2 < DF; ++dd2) acc = fmaf(s2[dd2], w2[dd2 * DF + t], acc);
    float h3 = fmaxf(acc, 0.f);
    float p = h3 * w3[t];
#pragma unroll
    for (int off = 32; off > 0; off >>= 1) p += __shfl_down(p, off);
    if ((t & 63) == 0) s_part[t >> 6] = p;
    __syncthreads();
    if (t == 0) {
        float s = s_part[0] + s_part[1] + b3[0];
        out[b] = 1.f / (1.f + __expf(-s));
    }
}

// ---------------------------------------------------------------------------
extern "C" void kernel_launch(void* const* d_in, const int* in_sizes, int n_in,
                              void* d_out, int out_size, void* d_ws, size_t ws_size,
                              hipStream_t stream) {
    const float* chs   = (const float*)d_in[0];
    const float* adj1  = (const float*)d_in[1];
    const float* dist  = (const float*)d_in[2];
    const float* valid = (const float*)d_in[3];
    const float* We    = (const float*)d_in[4];
    const float* Ww    = (const float*)d_in[5];
    const float* Wb    = (const float*)d_in[6];
    const float* A     = (const float*)d_in[7];
    const float* gw    = (const float*)d_in[8];
    const float* gb    = (const float*)d_in[9];
    const float* mu    = (const float*)d_in[10];
    const float* dev   = (const float*)d_in[11];
    const float* w0    = (const float*)d_in[12];
    const float* b0    = (const float*)d_in[13];
    const float* w1    = (const float*)d_in[14];
    const float* b1    = (const float*)d_in[15];
    const float* w2    = (const float*)d_in[16];
    const float* b2    = (const float*)d_in[17];
    const float* w3    = (const float*)d_in[18];
    const float* b3    = (const float*)d_in[19];
    float* out = (float*)d_out;

    const size_t SX  = (size_t)BB * NN * DD;   // 2,293,760
    const size_t SNN = (size_t)BB * NN * NN;   // 8,388,608
    float* ws  = (float*)d_ws;
    float* x   = ws;
    float* h   = x + SX;
    float* hA  = h + SX;
    float* hp1 = hA + SX;
    float* hp2 = hp1 + SX;
    float* e   = hp2 + SX;
    float* cm1 = e + SNN;
    float* cs1 = cm1 + BB * NN;
    float* cm2 = cs1 + BB * NN;
    float* cs2 = cm2 + BB * NN;
    float* g   = cs2 + BB * NN;

    k_embed<<<BB * NN / 32, 256, 0, stream>>>(chs, We, x);

    for (int k = 0; k < LL; ++k) {
        const float* Wwk = Ww + (size_t)k * DD * DD;
        const float* Wbk = Wb + (size_t)k * DD;
        const float* Ak  = A  + (size_t)k * DD * DD;
        const float* gwk = gw + (size_t)k * 2 * DD;
        const float* gbk = gb + k;
        k_wtrans<<<BB * NN / 32, 256, 0, stream>>>(x, Wwk, Wbk, Ak, h, hA);
        k_esym<<<dim3(NN / 32, NN / 32, BB), 256, 0, stream>>>(h, hA, e);
        k_colsm<<<dim3(NN / 256, BB), 256, 0, stream>>>(e, adj1, dist, mu, dev, cm1, cs1, cm2, cs2);
        k_hprime<<<dim3(NN / 8, BB), 256, 0, stream>>>(e, adj1, dist, mu, dev, h,
                                                       cm1, cs1, cm2, cs2, hp1, hp2);
        k_gate<<<BB * NN, 64, 0, stream>>>(hp1, hp2, gwk, gbk, x);
    }

    k_readout<<<BB, 256, 0, stream>>>(x, valid, g);
    k_mlp<<<BB, 128, 0, stream>>>(g, w0, b0, w1, b1, w2, b2, w3, b3, out);
}

// Round 2
// 1957.713 us; speedup vs baseline: 1.3655x; 1.3655x over previous
//
#include <hip/hip_runtime.h>

#define BB 32
#define NN 512
#define FIN 74
#define DD 140
#define DF 128
#define LL 4
#define NEGV (-9e15f)

// ---------------------------------------------------------------------------
// embed: x[b,n,d] = sum_f c_hs[b,n,f] * We[d,f]
// 32 rows per block; We staged transposed in LDS.
__global__ __launch_bounds__(256) void k_embed(const float* __restrict__ chs,
                                               const float* __restrict__ We,
                                               float* __restrict__ x) {
    __shared__ float s_we[FIN * 144];     // [f][d] padded stride 144
    __shared__ float s_in[32 * FIN];
    int bn0 = blockIdx.x * 32;
    int tid = threadIdx.x;
    for (int idx = tid; idx < DD * FIN; idx += 256) {
        int r = idx / FIN, c = idx % FIN;           // r=d, c=f
        s_we[c * 144 + r] = We[idx];
    }
    for (int idx = tid; idx < 32 * FIN; idx += 256)
        s_in[idx] = chs[(size_t)bn0 * FIN + idx];
    __syncthreads();
    int d = tid;
    if (d < DD) {
        float acc[32];
#pragma unroll
        for (int r = 0; r < 32; ++r) acc[r] = 0.f;
        for (int f = 0; f < FIN; ++f) {
            float w = s_we[f * 144 + d];
#pragma unroll
            for (int r = 0; r < 32; ++r) acc[r] = fmaf(s_in[r * FIN + f], w, acc[r]);
        }
#pragma unroll
        for (int r = 0; r < 32; ++r) x[(size_t)(bn0 + r) * DD + d] = acc[r];
    }
}

// ---------------------------------------------------------------------------
// wtrans: h = x@Ww^T + Wb ; hA = h@A   (32 rows per block)
__global__ __launch_bounds__(256) void k_wtrans(const float* __restrict__ x,
                                                const float* __restrict__ Ww,
                                                const float* __restrict__ Wb,
                                                const float* __restrict__ A,
                                                float* __restrict__ h,
                                                float* __restrict__ hA) {
    __shared__ float s_x[32 * DD];
    __shared__ float s_h[32 * DD];
    __shared__ float s_w[32 * 144];     // transposed weight chunk [f][d]
    int bn0 = blockIdx.x * 32;
    int tid = threadIdx.x;
    for (int idx = tid; idx < 32 * DD; idx += 256) s_x[idx] = x[(size_t)bn0 * DD + idx];
    float acc[32];
#pragma unroll
    for (int r = 0; r < 32; ++r) acc[r] = 0.f;
    int d = tid;
    for (int f0 = 0; f0 < DD; f0 += 32) {
        int fn = (DD - f0) < 32 ? (DD - f0) : 32;
        __syncthreads();
        for (int idx = tid; idx < fn * DD; idx += 256) {
            int rr = idx / fn, cc = idx % fn;        // rr = d (weight row), cc = f offset
            s_w[cc * 144 + rr] = Ww[rr * DD + f0 + cc];
        }
        __syncthreads();
        if (d < DD) {
            for (int f = 0; f < fn; ++f) {
                float w = s_w[f * 144 + d];
#pragma unroll
                for (int r = 0; r < 32; ++r) acc[r] = fmaf(s_x[r * DD + f0 + f], w, acc[r]);
            }
        }
    }
    if (d < DD) {
        float bias = Wb[d];
#pragma unroll
        for (int r = 0; r < 32; ++r) {
            float v = acc[r] + bias;
            s_h[r * DD + d] = v;
            h[(size_t)(bn0 + r) * DD + d] = v;
            acc[r] = 0.f;
        }
    }
    __syncthreads();
    if (d < DD) {
        for (int dd2 = 0; dd2 < DD; ++dd2) {
            float a = A[dd2 * DD + d];               // coalesced across d
#pragma unroll
            for (int r = 0; r < 32; ++r) acc[r] = fmaf(s_h[r * DD + dd2], a, acc[r]);
        }
#pragma unroll
        for (int r = 0; r < 32; ++r) hA[(size_t)(bn0 + r) * DD + d] = acc[r];
    }
}

// ---------------------------------------------------------------------------
// esym: e[b,i,j] = hA[b,i]·h[b,j] + h[b,i]·hA[b,j]
// 32x32 tile per block; j-side in LDS (XOR-swizzled), i-side global broadcast.
#define ESTRIDE 160
__global__ __launch_bounds__(256) void k_esym(const float* __restrict__ h,
                                              const float* __restrict__ hA,
                                              float* __restrict__ e) {
    __shared__ __align__(16) float s_hj[32 * ESTRIDE];
    __shared__ __align__(16) float s_aj[32 * ESTRIDE];
    int b = blockIdx.z;
    int j0 = blockIdx.x * 32;
    int i0 = blockIdx.y * 32;
    const float* hb = h + (size_t)b * NN * DD;
    const float* ab = hA + (size_t)b * NN * DD;
    int tid = threadIdx.x;
    for (int idx = tid; idx < 32 * DD; idx += 256) {
        int r = idx / DD, c = idx % DD;
        int sw = r * ESTRIDE + ((((c >> 2) << 2)) ^ ((r & 7) << 2)) + (c & 3);
        s_hj[sw] = hb[(size_t)(j0 + r) * DD + c];
        s_aj[sw] = ab[(size_t)(j0 + r) * DD + c];
    }
    __syncthreads();
    int tx = tid & 15, ty = tid >> 4;
    float acc[2][2] = {{0.f, 0.f}, {0.f, 0.f}};
    for (int k = 0; k < DD; k += 4) {
        float4 ai[2], hi[2];
#pragma unroll
        for (int ri = 0; ri < 2; ++ri) {
            int i = i0 + ty + 16 * ri;
            ai[ri] = *reinterpret_cast<const float4*>(&ab[(size_t)i * DD + k]);
            hi[ri] = *reinterpret_cast<const float4*>(&hb[(size_t)i * DD + k]);
        }
#pragma unroll
        for (int rj = 0; rj < 2; ++rj) {
            int row = tx + 16 * rj;
            int sw = row * ESTRIDE + (k ^ ((row & 7) << 2));
            float4 hj = *reinterpret_cast<const float4*>(&s_hj[sw]);
            float4 aj = *reinterpret_cast<const float4*>(&s_aj[sw]);
#pragma unroll
            for (int ri = 0; ri < 2; ++ri) {
                acc[ri][rj] += ai[ri].x * hj.x + ai[ri].y * hj.y + ai[ri].z * hj.z + ai[ri].w * hj.w
                             + hi[ri].x * aj.x + hi[ri].y * aj.y + hi[ri].z * aj.z + hi[ri].w * aj.w;
            }
        }
    }
#pragma unroll
    for (int ri = 0; ri < 2; ++ri)
#pragma unroll
        for (int rj = 0; rj < 2; ++rj)
            e[(size_t)b * NN * NN + (size_t)(i0 + ty + 16 * ri) * NN + (j0 + tx + 16 * rj)] = acc[ri][rj];
}

// ---------------------------------------------------------------------------
// column-softmax stats (softmax axis=1). KEY: e is symmetric (e+e^T) and adj1
// is symmetrized, and adj2>0 always (exp term >= e^-16), so column stats ==
// row stats -> read contiguous ROWS. One wave per (b,j); butterfly merge.
// cs outputs store RECIPROCAL of the denominator.
__global__ __launch_bounds__(256) void k_colsm(const float* __restrict__ e,
                                               const float* __restrict__ adj1,
                                               float* __restrict__ cm1, float* __restrict__ cs1,
                                               float* __restrict__ cm2, float* __restrict__ cs2) {
    int b = blockIdx.y;
    int j = blockIdx.x * 4 + (threadIdx.x >> 6);
    int lane = threadIdx.x & 63;
    const float4* e4 = reinterpret_cast<const float4*>(e + ((size_t)b * NN + j) * NN);
    const float4* a4 = reinterpret_cast<const float4*>(adj1 + ((size_t)b * NN + j) * NN);
    float v1[8], v2[8];
#pragma unroll
    for (int it = 0; it < 2; ++it) {
        float4 ev = e4[lane + 64 * it];
        float4 av = a4[lane + 64 * it];
        v2[it * 4 + 0] = ev.x; v1[it * 4 + 0] = av.x > 0.f ? ev.x : NEGV;
        v2[it * 4 + 1] = ev.y; v1[it * 4 + 1] = av.y > 0.f ? ev.y : NEGV;
        v2[it * 4 + 2] = ev.z; v1[it * 4 + 2] = av.z > 0.f ? ev.z : NEGV;
        v2[it * 4 + 3] = ev.w; v1[it * 4 + 3] = av.w > 0.f ? ev.w : NEGV;
    }
    float m1 = v1[0], m2 = v2[0];
#pragma unroll
    for (int q = 1; q < 8; ++q) { m1 = fmaxf(m1, v1[q]); m2 = fmaxf(m2, v2[q]); }
    float s1 = 0.f, s2 = 0.f;
#pragma unroll
    for (int q = 0; q < 8; ++q) { s1 += __expf(v1[q] - m1); s2 += __expf(v2[q] - m2); }
    // 64-lane butterfly merge of (m,s) pairs
#pragma unroll
    for (int off = 1; off < 64; off <<= 1) {
        float mo1 = __shfl_xor(m1, off), so1 = __shfl_xor(s1, off);
        float mo2 = __shfl_xor(m2, off), so2 = __shfl_xor(s2, off);
        float mn1 = fmaxf(m1, mo1);
        s1 = s1 * __expf(m1 - mn1) + so1 * __expf(mo1 - mn1);
        m1 = mn1;
        float mn2 = fmaxf(m2, mo2);
        s2 = s2 * __expf(m2 - mn2) + so2 * __expf(mo2 - mn2);
        m2 = mn2;
    }
    if (lane == 0) {
        cm1[b * NN + j] = m1; cs1[b * NN + j] = 1.0f / s1;
        cm2[b * NN + j] = m2; cs2[b * NN + j] = 1.0f / s2;
    }
}

// ---------------------------------------------------------------------------
// hprime (both paths fused): hp[b,i,d] = relu( sum_j att[b,i,j]*h[b,j,d] )
// att rebuilt on the fly. 8 i-rows per block, j chunked by 64 with h staged.
__global__ __launch_bounds__(256) void k_hprime(const float* __restrict__ e,
                                                const float* __restrict__ adj1,
                                                const float* __restrict__ dist,
                                                const float* __restrict__ mu_p,
                                                const float* __restrict__ dev_p,
                                                const float* __restrict__ h,
                                                const float* __restrict__ cm1, const float* __restrict__ cs1,
                                                const float* __restrict__ cm2, const float* __restrict__ cs2,
                                                float* __restrict__ hp1, float* __restrict__ hp2) {
    __shared__ __align__(16) float s_h[64 * DD];
    __shared__ __align__(16) float s_a1[8 * 64];
    __shared__ __align__(16) float s_a2[8 * 64];
    int b = blockIdx.y;
    int i0 = blockIdx.x * 8;
    int tid = threadIdx.x;
    float mu = mu_p[0], rdev = 1.0f / dev_p[0];
    float acc1[8], acc2[8];
#pragma unroll
    for (int r = 0; r < 8; ++r) { acc1[r] = 0.f; acc2[r] = 0.f; }
    const float* hb = h + (size_t)b * NN * DD;
    int d = tid;
    for (int j0 = 0; j0 < NN; j0 += 64) {
        __syncthreads();
        for (int idx = tid; idx < 64 * DD; idx += 256) s_h[idx] = hb[(size_t)j0 * DD + idx];
#pragma unroll
        for (int p = 0; p < 2; ++p) {
            int pr = tid + p * 256;
            int r = pr >> 6, jj = pr & 63;
            int i = i0 + r, j = j0 + jj;
            size_t off = (size_t)b * NN * NN + (size_t)i * NN + j;
            float ev = e[off];
            float a1 = adj1[off];
            float ddv = dist[off];
            float t = ddv - mu;
            float a2 = __expf(-t * t * rdev) + a1;
            float e1 = fminf(ev - cm1[b * NN + j], 0.f);
            float e2 = fminf(ev - cm2[b * NN + j], 0.f);
            s_a1[r * 64 + jj] = a1 > 0.f ? a1 * __expf(e1) * cs1[b * NN + j] : 0.f;
            s_a2[r * 64 + jj] = a2 * __expf(e2) * cs2[b * NN + j];
        }
        __syncthreads();
        if (d < DD) {
            for (int jj = 0; jj < 64; jj += 4) {
                float hv0 = s_h[(jj + 0) * DD + d];
                float hv1 = s_h[(jj + 1) * DD + d];
                float hv2 = s_h[(jj + 2) * DD + d];
                float hv3 = s_h[(jj + 3) * DD + d];
#pragma unroll
                for (int r = 0; r < 8; ++r) {
                    float4 a1v = *reinterpret_cast<const float4*>(&s_a1[r * 64 + jj]);
                    float4 a2v = *reinterpret_cast<const float4*>(&s_a2[r * 64 + jj]);
                    acc1[r] += a1v.x * hv0 + a1v.y * hv1 + a1v.z * hv2 + a1v.w * hv3;
                    acc2[r] += a2v.x * hv0 + a2v.y * hv1 + a2v.z * hv2 + a2v.w * hv3;
                }
            }
        }
    }
    if (d < DD) {
#pragma unroll
        for (int r = 0; r < 8; ++r) {
            size_t o = (size_t)b * NN * DD + (size_t)(i0 + r) * DD + d;
            hp1[o] = fmaxf(acc1[r], 0.f);
            hp2[o] = fmaxf(acc2[r], 0.f);
        }
    }
}

// ---------------------------------------------------------------------------
// gate + layer update: x = gate(x,hp2) - gate(x,hp1)   (one wave per node)
__global__ __launch_bounds__(64) void k_gate(const float* __restrict__ hp1,
                                             const float* __restrict__ hp2,
                                             const float* __restrict__ gw,
                                             const float* __restrict__ gb,
                                             float* __restrict__ x) {
    int bn = blockIdx.x;
    int t = threadIdx.x;
    const float* xr = x + (size_t)bn * DD;
    const float* h1r = hp1 + (size_t)bn * DD;
    const float* h2r = hp2 + (size_t)bn * DD;
    float xv[3], h1v[3], h2v[3];
    float sx = 0.f, s1 = 0.f, s2 = 0.f;
#pragma unroll
    for (int q = 0; q < 3; ++q) {
        int dd2 = t + 64 * q;
        bool ok = dd2 < DD;
        xv[q]  = ok ? xr[dd2]  : 0.f;
        h1v[q] = ok ? h1r[dd2] : 0.f;
        h2v[q] = ok ? h2r[dd2] : 0.f;
        float gl = ok ? gw[dd2] : 0.f;
        float gh = ok ? gw[DD + dd2] : 0.f;
        sx = fmaf(xv[q], gl, sx);
        s1 = fmaf(h1v[q], gh, s1);
        s2 = fmaf(h2v[q], gh, s2);
    }
#pragma unroll
    for (int off = 32; off > 0; off >>= 1) {
        sx += __shfl_down(sx, off);
        s1 += __shfl_down(s1, off);
        s2 += __shfl_down(s2, off);
    }
    float z1 = __shfl(sx + s1, 0);
    float z2 = __shfl(sx + s2, 0);
    float gbv = gb[0];
    float c1 = 1.f / (1.f + __expf(-(z1 + gbv)));
    float c2 = 1.f / (1.f + __expf(-(z2 + gbv)));
#pragma unroll
    for (int q = 0; q < 3; ++q) {
        int dd2 = t + 64 * q;
        if (dd2 < DD) {
            float xnew = (c2 - c1) * xv[q] + (1.f - c2) * h2v[q] - (1.f - c1) * h1v[q];
            x[(size_t)bn * DD + dd2] = xnew;
        }
    }
}

// ---------------------------------------------------------------------------
// readout: g[b,d] = sum_n x[b,n,d] * valid[b,n]
__global__ __launch_bounds__(256) void k_readout(const float* __restrict__ x,
                                                 const float* __restrict__ valid,
                                                 float* __restrict__ g) {
    int b = blockIdx.x;
    int t = threadIdx.x;
    if (t < DD) {
        float acc = 0.f;
        for (int n = 0; n < NN; ++n)
            acc = fmaf(x[((size_t)b * NN + n) * DD + t], valid[b * NN + n], acc);
        g[b * DD + t] = acc;
    }
}

// ---------------------------------------------------------------------------
// tiny MLP head: relu x3 + sigmoid
__global__ __launch_bounds__(128) void k_mlp(const float* __restrict__ g,
                                             const float* __restrict__ w0, const float* __restrict__ b0,
                                             const float* __restrict__ w1, const float* __restrict__ b1,
                                             const float* __restrict__ w2, const float* __restrict__ b2,
                                             const float* __restrict__ w3, const float* __restrict__ b3,
                                             float* __restrict__ out) {
    __shared__ float s0[DD];
    __shared__ float s1[DF];
    __shared__ float s2[DF];
    __shared__ float s_part[2];
    int b = blockIdx.x, t = threadIdx.x;
    for (int i = t; i < DD; i += 128) s0[i] = g[b * DD + i];
    __syncthreads();
    float acc = b0[t];
    for (int dd2 = 0; dd2 < DD; ++dd2) acc = fmaf(s0[dd2], w0[dd2 * DF + t], acc);
    s1[t] = fmaxf(acc, 0.f);
    __syncthreads();
    acc = b1[t];
    for (int dd2 = 0; dd2 < DF; ++dd2) acc = fmaf(s1[dd2], w1[dd2 * DF + t], acc);
    s2[t] = fmaxf(acc, 0.f);
    __syncthreads();
    acc = b2[t];
    for (int dd2 = 0; dd2 < DF; ++dd2) acc = fmaf(s2[dd2], w2[dd2 * DF + t], acc);
    float h3 = fmaxf(acc, 0.f);
    float p = h3 * w3[t];
#pragma unroll
    for (int off = 32; off > 0; off >>= 1) p += __shfl_down(p, off);
    if ((t & 63) == 0) s_part[t >> 6] = p;
    __syncthreads();
    if (t == 0) {
        float s = s_part[0] + s_part[1] + b3[0];
        out[b] = 1.f / (1.f + __expf(-s));
    }
}

// ---------------------------------------------------------------------------
extern "C" void kernel_launch(void* const* d_in, const int* in_sizes, int n_in,
                              void* d_out, int out_size, void* d_ws, size_t ws_size,
                              hipStream_t stream) {
    const float* chs   = (const float*)d_in[0];
    const float* adj1  = (const float*)d_in[1];
    const float* dist  = (const float*)d_in[2];
    const float* valid = (const float*)d_in[3];
    const float* We    = (const float*)d_in[4];
    const float* Ww    = (const float*)d_in[5];
    const float* Wb    = (const float*)d_in[6];
    const float* A     = (const float*)d_in[7];
    const float* gw    = (const float*)d_in[8];
    const float* gb    = (const float*)d_in[9];
    const float* mu    = (const float*)d_in[10];
    const float* dev   = (const float*)d_in[11];
    const float* w0    = (const float*)d_in[12];
    const float* b0    = (const float*)d_in[13];
    const float* w1    = (const float*)d_in[14];
    const float* b1    = (const float*)d_in[15];
    const float* w2    = (const float*)d_in[16];
    const float* b2    = (const float*)d_in[17];
    const float* w3    = (const float*)d_in[18];
    const float* b3    = (const float*)d_in[19];
    float* out = (float*)d_out;

    const size_t SX  = (size_t)BB * NN * DD;   // 2,293,760
    const size_t SNN = (size_t)BB * NN * NN;   // 8,388,608
    float* ws  = (float*)d_ws;
    float* x   = ws;
    float* h   = x + SX;
    float* hA  = h + SX;
    float* hp1 = hA + SX;
    float* hp2 = hp1 + SX;
    float* e   = hp2 + SX;
    float* cm1 = e + SNN;
    float* cs1 = cm1 + BB * NN;
    float* cm2 = cs1 + BB * NN;
    float* cs2 = cm2 + BB * NN;
    float* g   = cs2 + BB * NN;

    k_embed<<<BB * NN / 32, 256, 0, stream>>>(chs, We, x);

    for (int k = 0; k < LL; ++k) {
        const float* Wwk = Ww + (size_t)k * DD * DD;
        const float* Wbk = Wb + (size_t)k * DD;
        const float* Ak  = A  + (size_t)k * DD * DD;
        const float* gwk = gw + (size_t)k * 2 * DD;
        const float* gbk = gb + k;
        k_wtrans<<<BB * NN / 32, 256, 0, stream>>>(x, Wwk, Wbk, Ak, h, hA);
        k_esym<<<dim3(NN / 32, NN / 32, BB), 256, 0, stream>>>(h, hA, e);
        k_colsm<<<dim3(NN / 4, BB), 256, 0, stream>>>(e, adj1, cm1, cs1, cm2, cs2);
        k_hprime<<<dim3(NN / 8, BB), 256, 0, stream>>>(e, adj1, dist, mu, dev, h,
                                                       cm1, cs1, cm2, cs2, hp1, hp2);
        k_gate<<<BB * NN, 64, 0, stream>>>(hp1, hp2, gwk, gbk, x);
    }

    k_readout<<<BB, 256, 0, stream>>>(x, valid, g);
    k_mlp<<<BB, 128, 0, stream>>>(g, w0, b0, w1, b1, w2, b2, w3, b3, out);
}

// Round 3
// 851.217 us; speedup vs baseline: 3.1405x; 2.2999x over previous
//
#include <hip/hip_runtime.h>

#define BB 32
#define NN 512
#define FIN 74
#define DD 140
#define DP 160            // padded d (zero-filled 140..159), multiple of 32
#define DF 128
#define LL 4
#define NEGV (-9e15f)

typedef __attribute__((ext_vector_type(8))) short bf16x8;
typedef __attribute__((ext_vector_type(4))) float f32x4;

__device__ inline ushort f2bf(float x) {
    union { float f; unsigned u; } v; v.f = x;
    unsigned r = (v.u + 0x7FFFu + ((v.u >> 16) & 1u)) >> 16;   // RNE
    return (ushort)r;
}

// ---------------------------------------------------------------------------
// embed: x[b,n,d] = sum_f c_hs[b,n,f] * We[d,f]
__global__ __launch_bounds__(256) void k_embed(const float* __restrict__ chs,
                                               const float* __restrict__ We,
                                               float* __restrict__ x) {
    __shared__ float s_we[FIN * 144];
    __shared__ float s_in[32 * FIN];
    int bn0 = blockIdx.x * 32;
    int tid = threadIdx.x;
    for (int idx = tid; idx < DD * FIN; idx += 256) {
        int r = idx / FIN, c = idx % FIN;
        s_we[c * 144 + r] = We[idx];
    }
    for (int idx = tid; idx < 32 * FIN; idx += 256)
        s_in[idx] = chs[(size_t)bn0 * FIN + idx];
    __syncthreads();
    int d = tid;
    if (d < DD) {
        float acc[32];
#pragma unroll
        for (int r = 0; r < 32; ++r) acc[r] = 0.f;
        for (int f = 0; f < FIN; ++f) {
            float w = s_we[f * 144 + d];
#pragma unroll
            for (int r = 0; r < 32; ++r) acc[r] = fmaf(s_in[r * FIN + f], w, acc[r]);
        }
#pragma unroll
        for (int r = 0; r < 32; ++r) x[(size_t)(bn0 + r) * DD + d] = acc[r];
    }
}

// ---------------------------------------------------------------------------
// wtrans: h = x@Ww^T + Wb ; hA = h@A. Emits bf16: h_bf [BN][DP], hA_bf [BN][DP]
// (zero-padded), hT_bf [B][DP][NN]. fp32 h/hA are no longer materialized.
__global__ __launch_bounds__(256) void k_wtrans(const float* __restrict__ x,
                                                const float* __restrict__ Ww,
                                                const float* __restrict__ Wb,
                                                const float* __restrict__ A,
                                                ushort* __restrict__ h_bf,
                                                ushort* __restrict__ hA_bf,
                                                ushort* __restrict__ hT_bf) {
    __shared__ float s_x[32 * DD];
    __shared__ float s_h[32 * DD];
    __shared__ float s_w[32 * 144];
    int bn0 = blockIdx.x * 32;
    int b = bn0 >> 9, n0 = bn0 & (NN - 1);
    int tid = threadIdx.x;
    for (int idx = tid; idx < 32 * DD; idx += 256) s_x[idx] = x[(size_t)bn0 * DD + idx];
    float acc[32];
#pragma unroll
    for (int r = 0; r < 32; ++r) acc[r] = 0.f;
    int d = tid;
    for (int f0 = 0; f0 < DD; f0 += 32) {
        int fn = (DD - f0) < 32 ? (DD - f0) : 32;
        __syncthreads();
        for (int idx = tid; idx < fn * DD; idx += 256) {
            int rr = idx / fn, cc = idx % fn;
            s_w[cc * 144 + rr] = Ww[rr * DD + f0 + cc];
        }
        __syncthreads();
        if (d < DD) {
            for (int f = 0; f < fn; ++f) {
                float w = s_w[f * 144 + d];
#pragma unroll
                for (int r = 0; r < 32; ++r) acc[r] = fmaf(s_x[r * DD + f0 + f], w, acc[r]);
            }
        }
    }
    if (d < DD) {
        float bias = Wb[d];
#pragma unroll
        for (int r = 0; r < 32; ++r) {
            float v = acc[r] + bias;
            s_h[r * DD + d] = v;
            h_bf[(size_t)(bn0 + r) * DP + d] = f2bf(v);
            acc[r] = 0.f;
        }
    } else if (d < DP) {
#pragma unroll
        for (int r = 0; r < 32; ++r) h_bf[(size_t)(bn0 + r) * DP + d] = 0;
    }
    __syncthreads();
    if (d < DD) {
        for (int dd2 = 0; dd2 < DD; ++dd2) {
            float a = A[dd2 * DD + d];
#pragma unroll
            for (int r = 0; r < 32; ++r) acc[r] = fmaf(s_h[r * DD + dd2], a, acc[r]);
        }
#pragma unroll
        for (int r = 0; r < 32; ++r) hA_bf[(size_t)(bn0 + r) * DP + d] = f2bf(acc[r]);
    } else if (d < DP) {
#pragma unroll
        for (int r = 0; r < 32; ++r) hA_bf[(size_t)(bn0 + r) * DP + d] = 0;
    }
    // hT: [DP][NN] per batch, from s_h (transpose), zero rows d>=140
#pragma unroll
    for (int p = 0; p < DP / 8; ++p) {
        int dd2 = p * 8 + (tid >> 5), jj = tid & 31;
        ushort v = (dd2 < DD) ? f2bf(s_h[jj * DD + dd2]) : (ushort)0;
        hT_bf[((size_t)b * DP + dd2) * NN + n0 + jj] = v;
    }
}

// ---------------------------------------------------------------------------
// esym via MFMA: e[i][j] = hA_i·h_j + h_i·hA_j. 64x64 tile per block, 4 waves
// each own a 32x32 quadrant. All frags straight from global (L2-resident).
__global__ __launch_bounds__(256) void k_esym(const ushort* __restrict__ h_bf,
                                              const ushort* __restrict__ hA_bf,
                                              float* __restrict__ e) {
    int b = blockIdx.z;
    int i0 = blockIdx.y * 64, j0 = blockIdx.x * 64;
    int w = threadIdx.x >> 6, l = threadIdx.x & 63;
    int wm = w & 1, wn = w >> 1;
    int lr = l & 15, kg = l >> 4;
    const ushort* hb = h_bf + (size_t)b * NN * DP;
    const ushort* ab = hA_bf + (size_t)b * NN * DP;
    f32x4 acc[2][2];
#pragma unroll
    for (int mt = 0; mt < 2; ++mt)
#pragma unroll
        for (int nt = 0; nt < 2; ++nt) acc[mt][nt] = (f32x4)(0.f);
    size_t moff[2], noff[2];
#pragma unroll
    for (int t = 0; t < 2; ++t) {
        moff[t] = (size_t)(i0 + wm * 32 + t * 16 + lr) * DP;
        noff[t] = (size_t)(j0 + wn * 32 + t * 16 + lr) * DP;
    }
    for (int d0 = 0; d0 < DP; d0 += 32) {
        int off = d0 + kg * 8;
        bf16x8 am[2], hm[2], hn[2], an[2];
#pragma unroll
        for (int t = 0; t < 2; ++t) {
            am[t] = *reinterpret_cast<const bf16x8*>(ab + moff[t] + off);
            hm[t] = *reinterpret_cast<const bf16x8*>(hb + moff[t] + off);
            hn[t] = *reinterpret_cast<const bf16x8*>(hb + noff[t] + off);
            an[t] = *reinterpret_cast<const bf16x8*>(ab + noff[t] + off);
        }
#pragma unroll
        for (int mt = 0; mt < 2; ++mt)
#pragma unroll
            for (int nt = 0; nt < 2; ++nt) {
                acc[mt][nt] = __builtin_amdgcn_mfma_f32_16x16x32_bf16(am[mt], hn[nt], acc[mt][nt], 0, 0, 0);
                acc[mt][nt] = __builtin_amdgcn_mfma_f32_16x16x32_bf16(hm[mt], an[nt], acc[mt][nt], 0, 0, 0);
            }
    }
    float* eb = e + (size_t)b * NN * NN;
#pragma unroll
    for (int mt = 0; mt < 2; ++mt) {
        int rbase = i0 + wm * 32 + mt * 16 + kg * 4;
#pragma unroll
        for (int nt = 0; nt < 2; ++nt) {
            int col = j0 + wn * 32 + nt * 16 + lr;
#pragma unroll
            for (int r = 0; r < 4; ++r)
                eb[(size_t)(rbase + r) * NN + col] = acc[mt][nt][r];
        }
    }
}

// ---------------------------------------------------------------------------
// column-softmax stats (== row stats by symmetry). One wave per (b,j).
__global__ __launch_bounds__(256) void k_colsm(const float* __restrict__ e,
                                               const float* __restrict__ adj1,
                                               float* __restrict__ cm1, float* __restrict__ cs1,
                                               float* __restrict__ cm2, float* __restrict__ cs2) {
    int b = blockIdx.y;
    int j = blockIdx.x * 4 + (threadIdx.x >> 6);
    int lane = threadIdx.x & 63;
    const float4* e4 = reinterpret_cast<const float4*>(e + ((size_t)b * NN + j) * NN);
    const float4* a4 = reinterpret_cast<const float4*>(adj1 + ((size_t)b * NN + j) * NN);
    float v1[8], v2[8];
#pragma unroll
    for (int it = 0; it < 2; ++it) {
        float4 ev = e4[lane + 64 * it];
        float4 av = a4[lane + 64 * it];
        v2[it * 4 + 0] = ev.x; v1[it * 4 + 0] = av.x > 0.f ? ev.x : NEGV;
        v2[it * 4 + 1] = ev.y; v1[it * 4 + 1] = av.y > 0.f ? ev.y : NEGV;
        v2[it * 4 + 2] = ev.z; v1[it * 4 + 2] = av.z > 0.f ? ev.z : NEGV;
        v2[it * 4 + 3] = ev.w; v1[it * 4 + 3] = av.w > 0.f ? ev.w : NEGV;
    }
    float m1 = v1[0], m2 = v2[0];
#pragma unroll
    for (int q = 1; q < 8; ++q) { m1 = fmaxf(m1, v1[q]); m2 = fmaxf(m2, v2[q]); }
    float s1 = 0.f, s2 = 0.f;
#pragma unroll
    for (int q = 0; q < 8; ++q) { s1 += __expf(v1[q] - m1); s2 += __expf(v2[q] - m2); }
#pragma unroll
    for (int off = 1; off < 64; off <<= 1) {
        float mo1 = __shfl_xor(m1, off), so1 = __shfl_xor(s1, off);
        float mo2 = __shfl_xor(m2, off), so2 = __shfl_xor(s2, off);
        float mn1 = fmaxf(m1, mo1);
        s1 = s1 * __expf(m1 - mn1) + so1 * __expf(mo1 - mn1);
        m1 = mn1;
        float mn2 = fmaxf(m2, mo2);
        s2 = s2 * __expf(m2 - mn2) + so2 * __expf(mo2 - mn2);
        m2 = mn2;
    }
    if (lane == 0) {
        cm1[b * NN + j] = m1; cs1[b * NN + j] = 1.0f / s1;
        cm2[b * NN + j] = m2; cs2[b * NN + j] = 1.0f / s2;
    }
}

// ---------------------------------------------------------------------------
// hprime via MFMA: hp[i][d] = relu( att[i][:]@h[:][d] ), both paths.
// Per block: 32 i-rows; per 32-j chunk all 256 threads build att (fp32->bf16
// ->LDS), 4 waves = (m-tile x path) run 9 MFMAs vs hT (global, L2-resident).
__global__ __launch_bounds__(256) void k_hprime(const float* __restrict__ e,
                                                const float* __restrict__ adj1,
                                                const float* __restrict__ dist,
                                                const float* __restrict__ mu_p,
                                                const float* __restrict__ dev_p,
                                                const ushort* __restrict__ hT_bf,
                                                const float* __restrict__ cm1, const float* __restrict__ cs1,
                                                const float* __restrict__ cm2, const float* __restrict__ cs2,
                                                float* __restrict__ hp1, float* __restrict__ hp2) {
    __shared__ ushort s_att[2][32 * 40];   // stride 40 bf16 = 80B rows (16B aligned)
    int b = blockIdx.y, i0 = blockIdx.x * 32;
    int tid = threadIdx.x;
    int w = tid >> 6, l = tid & 63;
    int wm = w & 1, path = w >> 1;
    int lr = l & 15, kg = l >> 4;
    float mu = mu_p[0], rdev = 1.0f / dev_p[0];
    int ai = tid >> 3, aj4 = (tid & 7) * 4;
    const float* e_row = e + (size_t)b * NN * NN + (size_t)(i0 + ai) * NN;
    const float* a_row = adj1 + (size_t)b * NN * NN + (size_t)(i0 + ai) * NN;
    const float* d_row = dist + (size_t)b * NN * NN + (size_t)(i0 + ai) * NN;
    const float* cm1b = cm1 + b * NN;
    const float* cs1b = cs1 + b * NN;
    const float* cm2b = cm2 + b * NN;
    const float* cs2b = cs2 + b * NN;
    const ushort* hTb = hT_bf + (size_t)b * DP * NN;
    f32x4 acc[9];
#pragma unroll
    for (int nt = 0; nt < 9; ++nt) acc[nt] = (f32x4)(0.f);

    for (int j0 = 0; j0 < NN; j0 += 32) {
        __syncthreads();   // protect previous chunk's s_att reads
        float4 ev4 = *reinterpret_cast<const float4*>(e_row + j0 + aj4);
        float4 av4 = *reinterpret_cast<const float4*>(a_row + j0 + aj4);
        float4 dv4 = *reinterpret_cast<const float4*>(d_row + j0 + aj4);
        float evv[4] = {ev4.x, ev4.y, ev4.z, ev4.w};
        float avv[4] = {av4.x, av4.y, av4.z, av4.w};
        float dvv[4] = {dv4.x, dv4.y, dv4.z, dv4.w};
        ushort o1[4], o2[4];
#pragma unroll
        for (int c = 0; c < 4; ++c) {
            int j = j0 + aj4 + c;
            float a1 = avv[c];
            float t = dvv[c] - mu;
            float a2 = __expf(-t * t * rdev) + a1;
            float att1 = a1 > 0.f ? a1 * __expf(evv[c] - cm1b[j]) * cs1b[j] : 0.f;
            float att2 = a2 * __expf(evv[c] - cm2b[j]) * cs2b[j];
            o1[c] = f2bf(att1); o2[c] = f2bf(att2);
        }
        uint2 p1, p2;
        p1.x = (uint)o1[0] | ((uint)o1[1] << 16); p1.y = (uint)o1[2] | ((uint)o1[3] << 16);
        p2.x = (uint)o2[0] | ((uint)o2[1] << 16); p2.y = (uint)o2[2] | ((uint)o2[3] << 16);
        *reinterpret_cast<uint2*>(&s_att[0][ai * 40 + aj4]) = p1;
        *reinterpret_cast<uint2*>(&s_att[1][ai * 40 + aj4]) = p2;
        __syncthreads();
        bf16x8 afr = *reinterpret_cast<const bf16x8*>(&s_att[path][(wm * 16 + lr) * 40 + kg * 8]);
#pragma unroll
        for (int nt = 0; nt < 9; ++nt) {
            bf16x8 bfr = *reinterpret_cast<const bf16x8*>(hTb + (size_t)(nt * 16 + lr) * NN + j0 + kg * 8);
            acc[nt] = __builtin_amdgcn_mfma_f32_16x16x32_bf16(afr, bfr, acc[nt], 0, 0, 0);
        }
    }
    float* hp = path ? hp2 : hp1;
    int rbase = i0 + wm * 16 + kg * 4;
#pragma unroll
    for (int nt = 0; nt < 9; ++nt) {
        int col = nt * 16 + lr;
        if (col < DD) {
#pragma unroll
            for (int r = 0; r < 4; ++r)
                hp[(size_t)b * NN * DD + (size_t)(rbase + r) * DD + col] = fmaxf(acc[nt][r], 0.f);
        }
    }
}

// ---------------------------------------------------------------------------
// gate + layer update: x = gate(x,hp2) - gate(x,hp1)   (one wave per node)
__global__ __launch_bounds__(64) void k_gate(const float* __restrict__ hp1,
                                             const float* __restrict__ hp2,
                                             const float* __restrict__ gw,
                                             const float* __restrict__ gb,
                                             float* __restrict__ x) {
    int bn = blockIdx.x;
    int t = threadIdx.x;
    const float* xr = x + (size_t)bn * DD;
    const float* h1r = hp1 + (size_t)bn * DD;
    const float* h2r = hp2 + (size_t)bn * DD;
    float xv[3], h1v[3], h2v[3];
    float sx = 0.f, s1 = 0.f, s2 = 0.f;
#pragma unroll
    for (int q = 0; q < 3; ++q) {
        int dd2 = t + 64 * q;
        bool ok = dd2 < DD;
        xv[q]  = ok ? xr[dd2]  : 0.f;
        h1v[q] = ok ? h1r[dd2] : 0.f;
        h2v[q] = ok ? h2r[dd2] : 0.f;
        float gl = ok ? gw[dd2] : 0.f;
        float gh = ok ? gw[DD + dd2] : 0.f;
        sx = fmaf(xv[q], gl, sx);
        s1 = fmaf(h1v[q], gh, s1);
        s2 = fmaf(h2v[q], gh, s2);
    }
#pragma unroll
    for (int off = 32; off > 0; off >>= 1) {
        sx += __shfl_down(sx, off);
        s1 += __shfl_down(s1, off);
        s2 += __shfl_down(s2, off);
    }
    float z1 = __shfl(sx + s1, 0);
    float z2 = __shfl(sx + s2, 0);
    float gbv = gb[0];
    float c1 = 1.f / (1.f + __expf(-(z1 + gbv)));
    float c2 = 1.f / (1.f + __expf(-(z2 + gbv)));
#pragma unroll
    for (int q = 0; q < 3; ++q) {
        int dd2 = t + 64 * q;
        if (dd2 < DD) {
            float xnew = (c2 - c1) * xv[q] + (1.f - c2) * h2v[q] - (1.f - c1) * h1v[q];
            x[(size_t)bn * DD + dd2] = xnew;
        }
    }
}

// ---------------------------------------------------------------------------
// readout: g[b,d] = sum_n x[b,n,d] * valid[b,n]
__global__ __launch_bounds__(256) void k_readout(const float* __restrict__ x,
                                                 const float* __restrict__ valid,
                                                 float* __restrict__ g) {
    int b = blockIdx.x;
    int t = threadIdx.x;
    if (t < DD) {
        float acc = 0.f;
        for (int n = 0; n < NN; ++n)
            acc = fmaf(x[((size_t)b * NN + n) * DD + t], valid[b * NN + n], acc);
        g[b * DD + t] = acc;
    }
}

// ---------------------------------------------------------------------------
// tiny MLP head: relu x3 + sigmoid
__global__ __launch_bounds__(128) void k_mlp(const float* __restrict__ g,
                                             const float* __restrict__ w0, const float* __restrict__ b0,
                                             const float* __restrict__ w1, const float* __restrict__ b1,
                                             const float* __restrict__ w2, const float* __restrict__ b2,
                                             const float* __restrict__ w3, const float* __restrict__ b3,
                                             float* __restrict__ out) {
    __shared__ float s0[DD];
    __shared__ float s1[DF];
    __shared__ float s2[DF];
    __shared__ float s_part[2];
    int b = blockIdx.x, t = threadIdx.x;
    for (int i = t; i < DD; i += 128) s0[i] = g[b * DD + i];
    __syncthreads();
    float acc = b0[t];
    for (int dd2 = 0; dd2 < DD; ++dd2) acc = fmaf(s0[dd2], w0[dd2 * DF + t], acc);
    s1[t] = fmaxf(acc, 0.f);
    __syncthreads();
    acc = b1[t];
    for (int dd2 = 0; dd2 < DF; ++dd2) acc = fmaf(s1[dd2], w1[dd2 * DF + t], acc);
    s2[t] = fmaxf(acc, 0.f);
    __syncthreads();
    acc = b2[t];
    for (int dd2 = 0; dd2 < DF; ++dd2) acc = fmaf(s2[dd2], w2[dd2 * DF + t], acc);
    float h3 = fmaxf(acc, 0.f);
    float p = h3 * w3[t];
#pragma unroll
    for (int off = 32; off > 0; off >>= 1) p += __shfl_down(p, off);
    if ((t & 63) == 0) s_part[t >> 6] = p;
    __syncthreads();
    if (t == 0) {
        float s = s_part[0] + s_part[1] + b3[0];
        out[b] = 1.f / (1.f + __expf(-s));
    }
}

// ---------------------------------------------------------------------------
extern "C" void kernel_launch(void* const* d_in, const int* in_sizes, int n_in,
                              void* d_out, int out_size, void* d_ws, size_t ws_size,
                              hipStream_t stream) {
    const float* chs   = (const float*)d_in[0];
    const float* adj1  = (const float*)d_in[1];
    const float* dist  = (const float*)d_in[2];
    const float* valid = (const float*)d_in[3];
    const float* We    = (const float*)d_in[4];
    const float* Ww    = (const float*)d_in[5];
    const float* Wb    = (const float*)d_in[6];
    const float* A     = (const float*)d_in[7];
    const float* gw    = (const float*)d_in[8];
    const float* gb    = (const float*)d_in[9];
    const float* mu    = (const float*)d_in[10];
    const float* dev   = (const float*)d_in[11];
    const float* w0    = (const float*)d_in[12];
    const float* b0    = (const float*)d_in[13];
    const float* w1    = (const float*)d_in[14];
    const float* b1    = (const float*)d_in[15];
    const float* w2    = (const float*)d_in[16];
    const float* b2    = (const float*)d_in[17];
    const float* w3    = (const float*)d_in[18];
    const float* b3    = (const float*)d_in[19];
    float* out = (float*)d_out;

    const size_t SX  = (size_t)BB * NN * DD;
    const size_t SNN = (size_t)BB * NN * NN;
    const size_t SBF = (size_t)BB * NN * DP;   // bf16 array elem count
    float* ws  = (float*)d_ws;
    float* x   = ws;
    float* hp1 = x + SX;
    float* hp2 = hp1 + SX;
    float* e   = hp2 + SX;
    float* cm1 = e + SNN;
    float* cs1 = cm1 + BB * NN;
    float* cm2 = cs1 + BB * NN;
    float* cs2 = cm2 + BB * NN;
    float* g   = cs2 + BB * NN;
    ushort* h_bf  = (ushort*)(g + BB * DD);
    ushort* hA_bf = h_bf + SBF;
    ushort* hT_bf = hA_bf + SBF;

    k_embed<<<BB * NN / 32, 256, 0, stream>>>(chs, We, x);

    for (int k = 0; k < LL; ++k) {
        const float* Wwk = Ww + (size_t)k * DD * DD;
        const float* Wbk = Wb + (size_t)k * DD;
        const float* Ak  = A  + (size_t)k * DD * DD;
        const float* gwk = gw + (size_t)k * 2 * DD;
        const float* gbk = gb + k;
        k_wtrans<<<BB * NN / 32, 256, 0, stream>>>(x, Wwk, Wbk, Ak, h_bf, hA_bf, hT_bf);
        k_esym<<<dim3(NN / 64, NN / 64, BB), 256, 0, stream>>>(h_bf, hA_bf, e);
        k_colsm<<<dim3(NN / 4, BB), 256, 0, stream>>>(e, adj1, cm1, cs1, cm2, cs2);
        k_hprime<<<dim3(NN / 32, BB), 256, 0, stream>>>(e, adj1, dist, mu, dev, hT_bf,
                                                        cm1, cs1, cm2, cs2, hp1, hp2);
        k_gate<<<BB * NN, 64, 0, stream>>>(hp1, hp2, gwk, gbk, x);
    }

    k_readout<<<BB, 256, 0, stream>>>(x, valid, g);
    k_mlp<<<BB, 128, 0, stream>>>(g, w0, b0, w1, b1, w2, b2, w3, b3, out);
}

// Round 4
// 584.658 us; speedup vs baseline: 4.5723x; 1.4559x over previous
//
#include <hip/hip_runtime.h>

#define BB 32
#define NN 512
#define FIN 74
#define DD 140
#define DP 160            // padded d (zero-filled 140..159), multiple of 32
#define DF 128
#define LL 4
#define NEGV (-9e15f)

typedef __attribute__((ext_vector_type(8))) short bf16x8;
typedef __attribute__((ext_vector_type(4))) float f32x4;

__device__ inline ushort f2bf(float x) {
    union { float f; unsigned u; } v; v.f = x;
    unsigned r = (v.u + 0x7FFFu + ((v.u >> 16) & 1u)) >> 16;   // RNE
    return (ushort)r;
}

// ---------------------------------------------------------------------------
// prep weights: Wwb[k][d][f] = bf16(Ww[k][d][f]) padded; ATb[k][d][d2] =
// bf16(A[k][d2][d]) padded (transposed for contiguous B-frag reads).
__global__ __launch_bounds__(256) void k_prepw(const float* __restrict__ Ww,
                                               const float* __restrict__ A,
                                               ushort* __restrict__ Wwb,
                                               ushort* __restrict__ ATb) {
    int k = blockIdx.y;
    int idx = blockIdx.x * 256 + threadIdx.x;     // over DP*DP = 25600
    int d = idx / DP, f = idx % DP;
    const float* Wk = Ww + (size_t)k * DD * DD;
    const float* Ak = A + (size_t)k * DD * DD;
    ushort wv = 0, av = 0;
    if (d < DD && f < DD) {
        wv = f2bf(Wk[d * DD + f]);
        av = f2bf(Ak[f * DD + d]);
    }
    Wwb[(size_t)k * DP * DP + idx] = wv;
    ATb[(size_t)k * DP * DP + idx] = av;
}

// ---------------------------------------------------------------------------
// embed: x[b,n,d] = sum_f c_hs[b,n,f] * We[d,f]; also emits x_bf (padded).
__global__ __launch_bounds__(256) void k_embed(const float* __restrict__ chs,
                                               const float* __restrict__ We,
                                               float* __restrict__ x,
                                               ushort* __restrict__ x_bf) {
    __shared__ float s_we[FIN * 144];
    __shared__ float s_in[32 * FIN];
    int bn0 = blockIdx.x * 32;
    int tid = threadIdx.x;
    for (int idx = tid; idx < DD * FIN; idx += 256) {
        int r = idx / FIN, c = idx % FIN;
        s_we[c * 144 + r] = We[idx];
    }
    for (int idx = tid; idx < 32 * FIN; idx += 256)
        s_in[idx] = chs[(size_t)bn0 * FIN + idx];
    __syncthreads();
    int d = tid;
    if (d < DD) {
        float acc[32];
#pragma unroll
        for (int r = 0; r < 32; ++r) acc[r] = 0.f;
        for (int f = 0; f < FIN; ++f) {
            float w = s_we[f * 144 + d];
#pragma unroll
            for (int r = 0; r < 32; ++r) acc[r] = fmaf(s_in[r * FIN + f], w, acc[r]);
        }
#pragma unroll
        for (int r = 0; r < 32; ++r) {
            x[(size_t)(bn0 + r) * DD + d] = acc[r];
            x_bf[(size_t)(bn0 + r) * DP + d] = f2bf(acc[r]);
        }
    } else if (d < DP) {
#pragma unroll
        for (int r = 0; r < 32; ++r) x_bf[(size_t)(bn0 + r) * DP + d] = 0;
    }
}

// ---------------------------------------------------------------------------
// wtrans via MFMA: h = x@Ww^T + Wb ; hA = h@A.
// 32 rows/block, 4 waves = (row-half x col-half), acc[5] each, K=160.
// GEMM1 -> bf16 -> LDS -> barrier -> GEMM2 (A-frags from LDS) + hT transpose.
__global__ __launch_bounds__(256) void k_wtrans(const ushort* __restrict__ x_bf,
                                                const ushort* __restrict__ Wwb,
                                                const ushort* __restrict__ ATb,
                                                const float* __restrict__ Wb,
                                                ushort* __restrict__ h_bf,
                                                ushort* __restrict__ hA_bf,
                                                ushort* __restrict__ hT_bf) {
    __shared__ __align__(16) ushort s_h[32][168];   // stride 168: 336B rows, 16B-aligned
    int bn0 = blockIdx.x * 32;
    int b = bn0 >> 9, n0 = bn0 & (NN - 1);
    int tid = threadIdx.x;
    int w = tid >> 6, l = tid & 63;
    int wm = w & 1, wc = w >> 1;        // row half, col half
    int lr = l & 15, kg = l >> 4;
    const ushort* xrow = x_bf + (size_t)(bn0 + wm * 16 + lr) * DP;
    f32x4 acc[5];
#pragma unroll
    for (int nt = 0; nt < 5; ++nt) acc[nt] = (f32x4)(0.f);
    for (int f0 = 0; f0 < DP; f0 += 32) {
        bf16x8 a = *reinterpret_cast<const bf16x8*>(xrow + f0 + kg * 8);
#pragma unroll
        for (int nt = 0; nt < 5; ++nt) {
            int col = (wc * 5 + nt) * 16 + lr;
            bf16x8 bfr = *reinterpret_cast<const bf16x8*>(Wwb + (size_t)col * DP + f0 + kg * 8);
            acc[nt] = __builtin_amdgcn_mfma_f32_16x16x32_bf16(a, bfr, acc[nt], 0, 0, 0);
        }
    }
#pragma unroll
    for (int nt = 0; nt < 5; ++nt) {
        int col = (wc * 5 + nt) * 16 + lr;
        float bias = col < DD ? Wb[col] : 0.f;
#pragma unroll
        for (int r = 0; r < 4; ++r) {
            int rowl = wm * 16 + kg * 4 + r;
            float v = col < DD ? acc[nt][r] + bias : 0.f;
            ushort u = f2bf(v);
            s_h[rowl][col] = u;
            h_bf[(size_t)(bn0 + rowl) * DP + col] = u;
        }
        acc[nt] = (f32x4)(0.f);
    }
    __syncthreads();
    for (int f0 = 0; f0 < DP; f0 += 32) {
        bf16x8 a = *reinterpret_cast<const bf16x8*>(&s_h[wm * 16 + lr][f0 + kg * 8]);
#pragma unroll
        for (int nt = 0; nt < 5; ++nt) {
            int col = (wc * 5 + nt) * 16 + lr;
            bf16x8 bfr = *reinterpret_cast<const bf16x8*>(ATb + (size_t)col * DP + f0 + kg * 8);
            acc[nt] = __builtin_amdgcn_mfma_f32_16x16x32_bf16(a, bfr, acc[nt], 0, 0, 0);
        }
    }
#pragma unroll
    for (int nt = 0; nt < 5; ++nt) {
        int col = (wc * 5 + nt) * 16 + lr;
#pragma unroll
        for (int r = 0; r < 4; ++r)
            hA_bf[(size_t)(bn0 + wm * 16 + kg * 4 + r) * DP + col] = f2bf(acc[nt][r]);
    }
    // hT[d][n0..n0+32) from s_h (transpose); rows d>=140 are zero already.
    if (tid < DP) {
        int d = tid;
        ushort tmp[32];
#pragma unroll
        for (int nn = 0; nn < 32; ++nn) tmp[nn] = s_h[nn][d];
        ushort* dst = hT_bf + ((size_t)b * DP + d) * NN + n0;
#pragma unroll
        for (int q = 0; q < 4; ++q)
            *reinterpret_cast<bf16x8*>(dst + q * 8) = *reinterpret_cast<const bf16x8*>(tmp + q * 8);
    }
}

// ---------------------------------------------------------------------------
// esym via MFMA: e[i][j] = hA_i·h_j + h_i·hA_j. 64x64 tile per block, 4 waves
// each own a 32x32 quadrant. All frags straight from global (L2-resident).
__global__ __launch_bounds__(256) void k_esym(const ushort* __restrict__ h_bf,
                                              const ushort* __restrict__ hA_bf,
                                              float* __restrict__ e) {
    int b = blockIdx.z;
    int i0 = blockIdx.y * 64, j0 = blockIdx.x * 64;
    int w = threadIdx.x >> 6, l = threadIdx.x & 63;
    int wm = w & 1, wn = w >> 1;
    int lr = l & 15, kg = l >> 4;
    const ushort* hb = h_bf + (size_t)b * NN * DP;
    const ushort* ab = hA_bf + (size_t)b * NN * DP;
    f32x4 acc[2][2];
#pragma unroll
    for (int mt = 0; mt < 2; ++mt)
#pragma unroll
        for (int nt = 0; nt < 2; ++nt) acc[mt][nt] = (f32x4)(0.f);
    size_t moff[2], noff[2];
#pragma unroll
    for (int t = 0; t < 2; ++t) {
        moff[t] = (size_t)(i0 + wm * 32 + t * 16 + lr) * DP;
        noff[t] = (size_t)(j0 + wn * 32 + t * 16 + lr) * DP;
    }
    for (int d0 = 0; d0 < DP; d0 += 32) {
        int off = d0 + kg * 8;
        bf16x8 am[2], hm[2], hn[2], an[2];
#pragma unroll
        for (int t = 0; t < 2; ++t) {
            am[t] = *reinterpret_cast<const bf16x8*>(ab + moff[t] + off);
            hm[t] = *reinterpret_cast<const bf16x8*>(hb + moff[t] + off);
            hn[t] = *reinterpret_cast<const bf16x8*>(hb + noff[t] + off);
            an[t] = *reinterpret_cast<const bf16x8*>(ab + noff[t] + off);
        }
#pragma unroll
        for (int mt = 0; mt < 2; ++mt)
#pragma unroll
            for (int nt = 0; nt < 2; ++nt) {
                acc[mt][nt] = __builtin_amdgcn_mfma_f32_16x16x32_bf16(am[mt], hn[nt], acc[mt][nt], 0, 0, 0);
                acc[mt][nt] = __builtin_amdgcn_mfma_f32_16x16x32_bf16(hm[mt], an[nt], acc[mt][nt], 0, 0, 0);
            }
    }
    float* eb = e + (size_t)b * NN * NN;
#pragma unroll
    for (int mt = 0; mt < 2; ++mt) {
        int rbase = i0 + wm * 32 + mt * 16 + kg * 4;
#pragma unroll
        for (int nt = 0; nt < 2; ++nt) {
            int col = j0 + wn * 32 + nt * 16 + lr;
#pragma unroll
            for (int r = 0; r < 4; ++r)
                eb[(size_t)(rbase + r) * NN + col] = acc[mt][nt][r];
        }
    }
}

// ---------------------------------------------------------------------------
// column-softmax stats (== row stats by symmetry). One wave per (b,j).
__global__ __launch_bounds__(256) void k_colsm(const float* __restrict__ e,
                                               const float* __restrict__ adj1,
                                               float* __restrict__ cm1, float* __restrict__ cs1,
                                               float* __restrict__ cm2, float* __restrict__ cs2) {
    int b = blockIdx.y;
    int j = blockIdx.x * 4 + (threadIdx.x >> 6);
    int lane = threadIdx.x & 63;
    const float4* e4 = reinterpret_cast<const float4*>(e + ((size_t)b * NN + j) * NN);
    const float4* a4 = reinterpret_cast<const float4*>(adj1 + ((size_t)b * NN + j) * NN);
    float v1[8], v2[8];
#pragma unroll
    for (int it = 0; it < 2; ++it) {
        float4 ev = e4[lane + 64 * it];
        float4 av = a4[lane + 64 * it];
        v2[it * 4 + 0] = ev.x; v1[it * 4 + 0] = av.x > 0.f ? ev.x : NEGV;
        v2[it * 4 + 1] = ev.y; v1[it * 4 + 1] = av.y > 0.f ? ev.y : NEGV;
        v2[it * 4 + 2] = ev.z; v1[it * 4 + 2] = av.z > 0.f ? ev.z : NEGV;
        v2[it * 4 + 3] = ev.w; v1[it * 4 + 3] = av.w > 0.f ? ev.w : NEGV;
    }
    float m1 = v1[0], m2 = v2[0];
#pragma unroll
    for (int q = 1; q < 8; ++q) { m1 = fmaxf(m1, v1[q]); m2 = fmaxf(m2, v2[q]); }
    float s1 = 0.f, s2 = 0.f;
#pragma unroll
    for (int q = 0; q < 8; ++q) { s1 += __expf(v1[q] - m1); s2 += __expf(v2[q] - m2); }
#pragma unroll
    for (int off = 1; off < 64; off <<= 1) {
        float mo1 = __shfl_xor(m1, off), so1 = __shfl_xor(s1, off);
        float mo2 = __shfl_xor(m2, off), so2 = __shfl_xor(s2, off);
        float mn1 = fmaxf(m1, mo1);
        s1 = s1 * __expf(m1 - mn1) + so1 * __expf(mo1 - mn1);
        m1 = mn1;
        float mn2 = fmaxf(m2, mo2);
        s2 = s2 * __expf(m2 - mn2) + so2 * __expf(mo2 - mn2);
        m2 = mn2;
    }
    if (lane == 0) {
        cm1[b * NN + j] = m1; cs1[b * NN + j] = 1.0f / s1;
        cm2[b * NN + j] = m2; cs2[b * NN + j] = 1.0f / s2;
    }
}

// ---------------------------------------------------------------------------
// hprime via MFMA: hp[i][d] = relu( att[i][:]@h[:][d] ), both paths.
__global__ __launch_bounds__(256) void k_hprime(const float* __restrict__ e,
                                                const float* __restrict__ adj1,
                                                const float* __restrict__ dist,
                                                const float* __restrict__ mu_p,
                                                const float* __restrict__ dev_p,
                                                const ushort* __restrict__ hT_bf,
                                                const float* __restrict__ cm1, const float* __restrict__ cs1,
                                                const float* __restrict__ cm2, const float* __restrict__ cs2,
                                                float* __restrict__ hp1, float* __restrict__ hp2) {
    __shared__ ushort s_att[2][32 * 40];   // stride 40 bf16 = 80B rows (16B aligned)
    int b = blockIdx.y, i0 = blockIdx.x * 32;
    int tid = threadIdx.x;
    int w = tid >> 6, l = tid & 63;
    int wm = w & 1, path = w >> 1;
    int lr = l & 15, kg = l >> 4;
    float mu = mu_p[0], rdev = 1.0f / dev_p[0];
    int ai = tid >> 3, aj4 = (tid & 7) * 4;
    const float* e_row = e + (size_t)b * NN * NN + (size_t)(i0 + ai) * NN;
    const float* a_row = adj1 + (size_t)b * NN * NN + (size_t)(i0 + ai) * NN;
    const float* d_row = dist + (size_t)b * NN * NN + (size_t)(i0 + ai) * NN;
    const float* cm1b = cm1 + b * NN;
    const float* cs1b = cs1 + b * NN;
    const float* cm2b = cm2 + b * NN;
    const float* cs2b = cs2 + b * NN;
    const ushort* hTb = hT_bf + (size_t)b * DP * NN;
    f32x4 acc[9];
#pragma unroll
    for (int nt = 0; nt < 9; ++nt) acc[nt] = (f32x4)(0.f);

    for (int j0 = 0; j0 < NN; j0 += 32) {
        __syncthreads();   // protect previous chunk's s_att reads
        float4 ev4 = *reinterpret_cast<const float4*>(e_row + j0 + aj4);
        float4 av4 = *reinterpret_cast<const float4*>(a_row + j0 + aj4);
        float4 dv4 = *reinterpret_cast<const float4*>(d_row + j0 + aj4);
        float evv[4] = {ev4.x, ev4.y, ev4.z, ev4.w};
        float avv[4] = {av4.x, av4.y, av4.z, av4.w};
        float dvv[4] = {dv4.x, dv4.y, dv4.z, dv4.w};
        ushort o1[4], o2[4];
#pragma unroll
        for (int c = 0; c < 4; ++c) {
            int j = j0 + aj4 + c;
            float a1 = avv[c];
            float t = dvv[c] - mu;
            float a2 = __expf(-t * t * rdev) + a1;
            float att1 = a1 > 0.f ? a1 * __expf(evv[c] - cm1b[j]) * cs1b[j] : 0.f;
            float att2 = a2 * __expf(evv[c] - cm2b[j]) * cs2b[j];
            o1[c] = f2bf(att1); o2[c] = f2bf(att2);
        }
        uint2 p1, p2;
        p1.x = (uint)o1[0] | ((uint)o1[1] << 16); p1.y = (uint)o1[2] | ((uint)o1[3] << 16);
        p2.x = (uint)o2[0] | ((uint)o2[1] << 16); p2.y = (uint)o2[2] | ((uint)o2[3] << 16);
        *reinterpret_cast<uint2*>(&s_att[0][ai * 40 + aj4]) = p1;
        *reinterpret_cast<uint2*>(&s_att[1][ai * 40 + aj4]) = p2;
        __syncthreads();
        bf16x8 afr = *reinterpret_cast<const bf16x8*>(&s_att[path][(wm * 16 + lr) * 40 + kg * 8]);
#pragma unroll
        for (int nt = 0; nt < 9; ++nt) {
            bf16x8 bfr = *reinterpret_cast<const bf16x8*>(hTb + (size_t)(nt * 16 + lr) * NN + j0 + kg * 8);
            acc[nt] = __builtin_amdgcn_mfma_f32_16x16x32_bf16(afr, bfr, acc[nt], 0, 0, 0);
        }
    }
    float* hp = path ? hp2 : hp1;
    int rbase = i0 + wm * 16 + kg * 4;
#pragma unroll
    for (int nt = 0; nt < 9; ++nt) {
        int col = nt * 16 + lr;
        if (col < DD) {
#pragma unroll
            for (int r = 0; r < 4; ++r)
                hp[(size_t)b * NN * DD + (size_t)(rbase + r) * DD + col] = fmaxf(acc[nt][r], 0.f);
        }
    }
}

// ---------------------------------------------------------------------------
// gate + layer update: x = gate(x,hp2) - gate(x,hp1); also refresh x_bf.
__global__ __launch_bounds__(64) void k_gate(const float* __restrict__ hp1,
                                             const float* __restrict__ hp2,
                                             const float* __restrict__ gw,
                                             const float* __restrict__ gb,
                                             float* __restrict__ x,
                                             ushort* __restrict__ x_bf) {
    int bn = blockIdx.x;
    int t = threadIdx.x;
    const float* xr = x + (size_t)bn * DD;
    const float* h1r = hp1 + (size_t)bn * DD;
    const float* h2r = hp2 + (size_t)bn * DD;
    float xv[3], h1v[3], h2v[3];
    float sx = 0.f, s1 = 0.f, s2 = 0.f;
#pragma unroll
    for (int q = 0; q < 3; ++q) {
        int dd2 = t + 64 * q;
        bool ok = dd2 < DD;
        xv[q]  = ok ? xr[dd2]  : 0.f;
        h1v[q] = ok ? h1r[dd2] : 0.f;
        h2v[q] = ok ? h2r[dd2] : 0.f;
        float gl = ok ? gw[dd2] : 0.f;
        float gh = ok ? gw[DD + dd2] : 0.f;
        sx = fmaf(xv[q], gl, sx);
        s1 = fmaf(h1v[q], gh, s1);
        s2 = fmaf(h2v[q], gh, s2);
    }
#pragma unroll
    for (int off = 32; off > 0; off >>= 1) {
        sx += __shfl_down(sx, off);
        s1 += __shfl_down(s1, off);
        s2 += __shfl_down(s2, off);
    }
    float z1 = __shfl(sx + s1, 0);
    float z2 = __shfl(sx + s2, 0);
    float gbv = gb[0];
    float c1 = 1.f / (1.f + __expf(-(z1 + gbv)));
    float c2 = 1.f / (1.f + __expf(-(z2 + gbv)));
#pragma unroll
    for (int q = 0; q < 3; ++q) {
        int dd2 = t + 64 * q;
        if (dd2 < DD) {
            float xnew = (c2 - c1) * xv[q] + (1.f - c2) * h2v[q] - (1.f - c1) * h1v[q];
            x[(size_t)bn * DD + dd2] = xnew;
            x_bf[(size_t)bn * DP + dd2] = f2bf(xnew);
        }
    }
}

// ---------------------------------------------------------------------------
// readout: g[b,d] = sum_n x[b,n,d] * valid[b,n]
__global__ __launch_bounds__(256) void k_readout(const float* __restrict__ x,
                                                 const float* __restrict__ valid,
                                                 float* __restrict__ g) {
    int b = blockIdx.x;
    int t = threadIdx.x;
    if (t < DD) {
        float acc = 0.f;
        for (int n = 0; n < NN; ++n)
            acc = fmaf(x[((size_t)b * NN + n) * DD + t], valid[b * NN + n], acc);
        g[b * DD + t] = acc;
    }
}

// ---------------------------------------------------------------------------
// tiny MLP head: relu x3 + sigmoid
__global__ __launch_bounds__(128) void k_mlp(const float* __restrict__ g,
                                             const float* __restrict__ w0, const float* __restrict__ b0,
                                             const float* __restrict__ w1, const float* __restrict__ b1,
                                             const float* __restrict__ w2, const float* __restrict__ b2,
                                             const float* __restrict__ w3, const float* __restrict__ b3,
                                             float* __restrict__ out) {
    __shared__ float s0[DD];
    __shared__ float s1[DF];
    __shared__ float s2[DF];
    __shared__ float s_part[2];
    int b = blockIdx.x, t = threadIdx.x;
    for (int i = t; i < DD; i += 128) s0[i] = g[b * DD + i];
    __syncthreads();
    float acc = b0[t];
    for (int dd2 = 0; dd2 < DD; ++dd2) acc = fmaf(s0[dd2], w0[dd2 * DF + t], acc);
    s1[t] = fmaxf(acc, 0.f);
    __syncthreads();
    acc = b1[t];
    for (int dd2 = 0; dd2 < DF; ++dd2) acc = fmaf(s1[dd2], w1[dd2 * DF + t], acc);
    s2[t] = fmaxf(acc, 0.f);
    __syncthreads();
    acc = b2[t];
    for (int dd2 = 0; dd2 < DF; ++dd2) acc = fmaf(s2[dd2], w2[dd2 * DF + t], acc);
    float h3 = fmaxf(acc, 0.f);
    float p = h3 * w3[t];
#pragma unroll
    for (int off = 32; off > 0; off >>= 1) p += __shfl_down(p, off);
    if ((t & 63) == 0) s_part[t >> 6] = p;
    __syncthreads();
    if (t == 0) {
        float s = s_part[0] + s_part[1] + b3[0];
        out[b] = 1.f / (1.f + __expf(-s));
    }
}

// ---------------------------------------------------------------------------
extern "C" void kernel_launch(void* const* d_in, const int* in_sizes, int n_in,
                              void* d_out, int out_size, void* d_ws, size_t ws_size,
                              hipStream_t stream) {
    const float* chs   = (const float*)d_in[0];
    const float* adj1  = (const float*)d_in[1];
    const float* dist  = (const float*)d_in[2];
    const float* valid = (const float*)d_in[3];
    const float* We    = (const float*)d_in[4];
    const float* Ww    = (const float*)d_in[5];
    const float* Wb    = (const float*)d_in[6];
    const float* A     = (const float*)d_in[7];
    const float* gw    = (const float*)d_in[8];
    const float* gb    = (const float*)d_in[9];
    const float* mu    = (const float*)d_in[10];
    const float* dev   = (const float*)d_in[11];
    const float* w0    = (const float*)d_in[12];
    const float* b0    = (const float*)d_in[13];
    const float* w1    = (const float*)d_in[14];
    const float* b1    = (const float*)d_in[15];
    const float* w2    = (const float*)d_in[16];
    const float* b2    = (const float*)d_in[17];
    const float* w3    = (const float*)d_in[18];
    const float* b3    = (const float*)d_in[19];
    float* out = (float*)d_out;

    const size_t SX  = (size_t)BB * NN * DD;
    const size_t SNN = (size_t)BB * NN * NN;
    const size_t SBF = (size_t)BB * NN * DP;   // bf16 array elem count
    float* ws  = (float*)d_ws;
    float* x   = ws;
    float* hp1 = x + SX;
    float* hp2 = hp1 + SX;
    float* e   = hp2 + SX;
    float* cm1 = e + SNN;
    float* cs1 = cm1 + BB * NN;
    float* cm2 = cs1 + BB * NN;
    float* cs2 = cm2 + BB * NN;
    float* g   = cs2 + BB * NN;
    ushort* h_bf  = (ushort*)(g + BB * DD);
    ushort* hA_bf = h_bf + SBF;
    ushort* hT_bf = hA_bf + SBF;
    ushort* x_bf  = hT_bf + SBF;
    ushort* Wwb   = x_bf + SBF;
    ushort* ATb   = Wwb + (size_t)LL * DP * DP;

    k_prepw<<<dim3(DP * DP / 256, LL), 256, 0, stream>>>(Ww, A, Wwb, ATb);
    k_embed<<<BB * NN / 32, 256, 0, stream>>>(chs, We, x, x_bf);

    for (int k = 0; k < LL; ++k) {
        const ushort* Wwbk = Wwb + (size_t)k * DP * DP;
        const ushort* ATbk = ATb + (size_t)k * DP * DP;
        const float* Wbk = Wb + (size_t)k * DD;
        const float* gwk = gw + (size_t)k * 2 * DD;
        const float* gbk = gb + k;
        k_wtrans<<<BB * NN / 32, 256, 0, stream>>>(x_bf, Wwbk, ATbk, Wbk, h_bf, hA_bf, hT_bf);
        k_esym<<<dim3(NN / 64, NN / 64, BB), 256, 0, stream>>>(h_bf, hA_bf, e);
        k_colsm<<<dim3(NN / 4, BB), 256, 0, stream>>>(e, adj1, cm1, cs1, cm2, cs2);
        k_hprime<<<dim3(NN / 32, BB), 256, 0, stream>>>(e, adj1, dist, mu, dev, hT_bf,
                                                        cm1, cs1, cm2, cs2, hp1, hp2);
        k_gate<<<BB * NN, 64, 0, stream>>>(hp1, hp2, gwk, gbk, x, x_bf);
    }

    k_readout<<<BB, 256, 0, stream>>>(x, valid, g);
    k_mlp<<<BB, 128, 0, stream>>>(g, w0, b0, w1, b1, w2, b2, w3, b3, out);
}

// Round 5
// 513.740 us; speedup vs baseline: 5.2035x; 1.1380x over previous
//
#include <hip/hip_runtime.h>
#include <hip/hip_fp16.h>

#define BB 32
#define NN 512
#define FIN 74
#define DD 140
#define DP 160            // padded d (zero-filled 140..159), multiple of 32
#define DF 128
#define LL 4
#define NEGV (-9e15f)

typedef __attribute__((ext_vector_type(8))) short bf16x8;
typedef __attribute__((ext_vector_type(4))) float f32x4;

__device__ inline ushort f2bf(float x) {
    union { float f; unsigned u; } v; v.f = x;
    unsigned r = (v.u + 0x7FFFu + ((v.u >> 16) & 1u)) >> 16;   // RNE
    return (ushort)r;
}
__device__ inline ushort f2h_bits(float x) {
    __half h = __float2half(x);
    union { __half h; ushort u; } c; c.h = h; return c.u;
}
__device__ inline float h2f_bits(ushort u) {
    union { __half h; ushort u; } c; c.u = u; return __half2float(c.h);
}

// ---------------------------------------------------------------------------
// prep adjacency: adjp[b,i,j] = fp16(exp(-(dist-mu)^2/dev) + a1), sign bit =
// (a1>0). a1 is exactly 0/1; exp term >= e^-16 ~ 1.1e-7 > fp16 min subnormal.
__global__ __launch_bounds__(256) void k_prepa(const float* __restrict__ adj1,
                                               const float* __restrict__ dist,
                                               const float* __restrict__ mu_p,
                                               const float* __restrict__ dev_p,
                                               ushort* __restrict__ adjp) {
    float mu = mu_p[0], rdev = 1.0f / dev_p[0];
    size_t base = ((size_t)blockIdx.x * 256 + threadIdx.x) * 4;
    float4 av = *reinterpret_cast<const float4*>(adj1 + base);
    float4 dv = *reinterpret_cast<const float4*>(dist + base);
    float aa[4] = {av.x, av.y, av.z, av.w};
    float dd[4] = {dv.x, dv.y, dv.z, dv.w};
    ushort o[4];
#pragma unroll
    for (int c = 0; c < 4; ++c) {
        float t = dd[c] - mu;
        float a2 = __expf(-t * t * rdev) + aa[c];
        ushort h = f2h_bits(a2);
        if (aa[c] > 0.f) h |= 0x8000u;
        o[c] = h;
    }
    uint2 pk;
    pk.x = (uint)o[0] | ((uint)o[1] << 16);
    pk.y = (uint)o[2] | ((uint)o[3] << 16);
    *reinterpret_cast<uint2*>(adjp + base) = pk;
}

// ---------------------------------------------------------------------------
// prep weights: Wwb[k][d][f] = bf16(Ww[k][d][f]) padded; ATb[k][d][d2] =
// bf16(A[k][d2][d]) padded (transposed for contiguous B-frag reads).
__global__ __launch_bounds__(256) void k_prepw(const float* __restrict__ Ww,
                                               const float* __restrict__ A,
                                               ushort* __restrict__ Wwb,
                                               ushort* __restrict__ ATb) {
    int k = blockIdx.y;
    int idx = blockIdx.x * 256 + threadIdx.x;     // over DP*DP = 25600
    int d = idx / DP, f = idx % DP;
    const float* Wk = Ww + (size_t)k * DD * DD;
    const float* Ak = A + (size_t)k * DD * DD;
    ushort wv = 0, av = 0;
    if (d < DD && f < DD) {
        wv = f2bf(Wk[d * DD + f]);
        av = f2bf(Ak[f * DD + d]);
    }
    Wwb[(size_t)k * DP * DP + idx] = wv;
    ATb[(size_t)k * DP * DP + idx] = av;
}

// ---------------------------------------------------------------------------
// embed: x[b,n,d] = sum_f c_hs[b,n,f] * We[d,f]; also emits x_bf (padded).
__global__ __launch_bounds__(256) void k_embed(const float* __restrict__ chs,
                                               const float* __restrict__ We,
                                               float* __restrict__ x,
                                               ushort* __restrict__ x_bf) {
    __shared__ float s_we[FIN * 144];
    __shared__ float s_in[32 * FIN];
    int bn0 = blockIdx.x * 32;
    int tid = threadIdx.x;
    for (int idx = tid; idx < DD * FIN; idx += 256) {
        int r = idx / FIN, c = idx % FIN;
        s_we[c * 144 + r] = We[idx];
    }
    for (int idx = tid; idx < 32 * FIN; idx += 256)
        s_in[idx] = chs[(size_t)bn0 * FIN + idx];
    __syncthreads();
    int d = tid;
    if (d < DD) {
        float acc[32];
#pragma unroll
        for (int r = 0; r < 32; ++r) acc[r] = 0.f;
        for (int f = 0; f < FIN; ++f) {
            float w = s_we[f * 144 + d];
#pragma unroll
            for (int r = 0; r < 32; ++r) acc[r] = fmaf(s_in[r * FIN + f], w, acc[r]);
        }
#pragma unroll
        for (int r = 0; r < 32; ++r) {
            x[(size_t)(bn0 + r) * DD + d] = acc[r];
            x_bf[(size_t)(bn0 + r) * DP + d] = f2bf(acc[r]);
        }
    } else if (d < DP) {
#pragma unroll
        for (int r = 0; r < 32; ++r) x_bf[(size_t)(bn0 + r) * DP + d] = 0;
    }
}

// ---------------------------------------------------------------------------
// wtrans via MFMA: h = x@Ww^T + Wb ; hA = h@A.
__global__ __launch_bounds__(256) void k_wtrans(const ushort* __restrict__ x_bf,
                                                const ushort* __restrict__ Wwb,
                                                const ushort* __restrict__ ATb,
                                                const float* __restrict__ Wb,
                                                ushort* __restrict__ h_bf,
                                                ushort* __restrict__ hA_bf,
                                                ushort* __restrict__ hT_bf) {
    __shared__ __align__(16) ushort s_h[32][168];
    int bn0 = blockIdx.x * 32;
    int b = bn0 >> 9, n0 = bn0 & (NN - 1);
    int tid = threadIdx.x;
    int w = tid >> 6, l = tid & 63;
    int wm = w & 1, wc = w >> 1;
    int lr = l & 15, kg = l >> 4;
    const ushort* xrow = x_bf + (size_t)(bn0 + wm * 16 + lr) * DP;
    f32x4 acc[5];
#pragma unroll
    for (int nt = 0; nt < 5; ++nt) acc[nt] = (f32x4)(0.f);
    for (int f0 = 0; f0 < DP; f0 += 32) {
        bf16x8 a = *reinterpret_cast<const bf16x8*>(xrow + f0 + kg * 8);
#pragma unroll
        for (int nt = 0; nt < 5; ++nt) {
            int col = (wc * 5 + nt) * 16 + lr;
            bf16x8 bfr = *reinterpret_cast<const bf16x8*>(Wwb + (size_t)col * DP + f0 + kg * 8);
            acc[nt] = __builtin_amdgcn_mfma_f32_16x16x32_bf16(a, bfr, acc[nt], 0, 0, 0);
        }
    }
#pragma unroll
    for (int nt = 0; nt < 5; ++nt) {
        int col = (wc * 5 + nt) * 16 + lr;
        float bias = col < DD ? Wb[col] : 0.f;
#pragma unroll
        for (int r = 0; r < 4; ++r) {
            int rowl = wm * 16 + kg * 4 + r;
            float v = col < DD ? acc[nt][r] + bias : 0.f;
            ushort u = f2bf(v);
            s_h[rowl][col] = u;
            h_bf[(size_t)(bn0 + rowl) * DP + col] = u;
        }
        acc[nt] = (f32x4)(0.f);
    }
    __syncthreads();
    for (int f0 = 0; f0 < DP; f0 += 32) {
        bf16x8 a = *reinterpret_cast<const bf16x8*>(&s_h[wm * 16 + lr][f0 + kg * 8]);
#pragma unroll
        for (int nt = 0; nt < 5; ++nt) {
            int col = (wc * 5 + nt) * 16 + lr;
            bf16x8 bfr = *reinterpret_cast<const bf16x8*>(ATb + (size_t)col * DP + f0 + kg * 8);
            acc[nt] = __builtin_amdgcn_mfma_f32_16x16x32_bf16(a, bfr, acc[nt], 0, 0, 0);
        }
    }
#pragma unroll
    for (int nt = 0; nt < 5; ++nt) {
        int col = (wc * 5 + nt) * 16 + lr;
#pragma unroll
        for (int r = 0; r < 4; ++r)
            hA_bf[(size_t)(bn0 + wm * 16 + kg * 4 + r) * DP + col] = f2bf(acc[nt][r]);
    }
    if (tid < DP) {
        int d = tid;
        ushort tmp[32];
#pragma unroll
        for (int nn = 0; nn < 32; ++nn) tmp[nn] = s_h[nn][d];
        ushort* dst = hT_bf + ((size_t)b * DP + d) * NN + n0;
#pragma unroll
        for (int q = 0; q < 4; ++q)
            *reinterpret_cast<bf16x8*>(dst + q * 8) = *reinterpret_cast<const bf16x8*>(tmp + q * 8);
    }
}

// ---------------------------------------------------------------------------
// esym via MFMA: e[i][j] = hA_i·h_j + h_i·hA_j.
__global__ __launch_bounds__(256) void k_esym(const ushort* __restrict__ h_bf,
                                              const ushort* __restrict__ hA_bf,
                                              float* __restrict__ e) {
    int b = blockIdx.z;
    int i0 = blockIdx.y * 64, j0 = blockIdx.x * 64;
    int w = threadIdx.x >> 6, l = threadIdx.x & 63;
    int wm = w & 1, wn = w >> 1;
    int lr = l & 15, kg = l >> 4;
    const ushort* hb = h_bf + (size_t)b * NN * DP;
    const ushort* ab = hA_bf + (size_t)b * NN * DP;
    f32x4 acc[2][2];
#pragma unroll
    for (int mt = 0; mt < 2; ++mt)
#pragma unroll
        for (int nt = 0; nt < 2; ++nt) acc[mt][nt] = (f32x4)(0.f);
    size_t moff[2], noff[2];
#pragma unroll
    for (int t = 0; t < 2; ++t) {
        moff[t] = (size_t)(i0 + wm * 32 + t * 16 + lr) * DP;
        noff[t] = (size_t)(j0 + wn * 32 + t * 16 + lr) * DP;
    }
    for (int d0 = 0; d0 < DP; d0 += 32) {
        int off = d0 + kg * 8;
        bf16x8 am[2], hm[2], hn[2], an[2];
#pragma unroll
        for (int t = 0; t < 2; ++t) {
            am[t] = *reinterpret_cast<const bf16x8*>(ab + moff[t] + off);
            hm[t] = *reinterpret_cast<const bf16x8*>(hb + moff[t] + off);
            hn[t] = *reinterpret_cast<const bf16x8*>(hb + noff[t] + off);
            an[t] = *reinterpret_cast<const bf16x8*>(ab + noff[t] + off);
        }
#pragma unroll
        for (int mt = 0; mt < 2; ++mt)
#pragma unroll
            for (int nt = 0; nt < 2; ++nt) {
                acc[mt][nt] = __builtin_amdgcn_mfma_f32_16x16x32_bf16(am[mt], hn[nt], acc[mt][nt], 0, 0, 0);
                acc[mt][nt] = __builtin_amdgcn_mfma_f32_16x16x32_bf16(hm[mt], an[nt], acc[mt][nt], 0, 0, 0);
            }
    }
    float* eb = e + (size_t)b * NN * NN;
#pragma unroll
    for (int mt = 0; mt < 2; ++mt) {
        int rbase = i0 + wm * 32 + mt * 16 + kg * 4;
#pragma unroll
        for (int nt = 0; nt < 2; ++nt) {
            int col = j0 + wn * 32 + nt * 16 + lr;
#pragma unroll
            for (int r = 0; r < 4; ++r)
                eb[(size_t)(rbase + r) * NN + col] = acc[mt][nt][r];
        }
    }
}

// ---------------------------------------------------------------------------
// column-softmax stats (== row stats by symmetry). One wave per (b,j).
// mask from adjp sign bit; path2 includes all (adj2>0 always).
__global__ __launch_bounds__(256) void k_colsm(const float* __restrict__ e,
                                               const ushort* __restrict__ adjp,
                                               float* __restrict__ cm1, float* __restrict__ cs1,
                                               float* __restrict__ cm2, float* __restrict__ cs2) {
    int b = blockIdx.y;
    int j = blockIdx.x * 4 + (threadIdx.x >> 6);
    int lane = threadIdx.x & 63;
    const float4* e4 = reinterpret_cast<const float4*>(e + ((size_t)b * NN + j) * NN);
    const uint2* p4 = reinterpret_cast<const uint2*>(adjp + ((size_t)b * NN + j) * NN);
    float v1[8], v2[8];
#pragma unroll
    for (int it = 0; it < 2; ++it) {
        float4 ev = e4[lane + 64 * it];
        uint2 pv = p4[lane + 64 * it];
        float evv[4] = {ev.x, ev.y, ev.z, ev.w};
        uint mk[4] = {pv.x & 0x8000u, pv.x & 0x80000000u, pv.y & 0x8000u, pv.y & 0x80000000u};
#pragma unroll
        for (int c = 0; c < 4; ++c) {
            v2[it * 4 + c] = evv[c];
            v1[it * 4 + c] = mk[c] ? evv[c] : NEGV;
        }
    }
    float m1 = v1[0], m2 = v2[0];
#pragma unroll
    for (int q = 1; q < 8; ++q) { m1 = fmaxf(m1, v1[q]); m2 = fmaxf(m2, v2[q]); }
    float s1 = 0.f, s2 = 0.f;
#pragma unroll
    for (int q = 0; q < 8; ++q) { s1 += __expf(v1[q] - m1); s2 += __expf(v2[q] - m2); }
#pragma unroll
    for (int off = 1; off < 64; off <<= 1) {
        float mo1 = __shfl_xor(m1, off), so1 = __shfl_xor(s1, off);
        float mo2 = __shfl_xor(m2, off), so2 = __shfl_xor(s2, off);
        float mn1 = fmaxf(m1, mo1);
        s1 = s1 * __expf(m1 - mn1) + so1 * __expf(mo1 - mn1);
        m1 = mn1;
        float mn2 = fmaxf(m2, mo2);
        s2 = s2 * __expf(m2 - mn2) + so2 * __expf(mo2 - mn2);
        m2 = mn2;
    }
    if (lane == 0) {
        cm1[b * NN + j] = m1; cs1[b * NN + j] = 1.0f / s1;
        cm2[b * NN + j] = m2; cs2[b * NN + j] = 1.0f / s2;
    }
}

// ---------------------------------------------------------------------------
// hprime via MFMA, double-buffered: hp[i][d] = relu( att[i][:]@h[:][d] ).
// 16 i-rows/block (1024 blocks). Col stats staged in LDS. 1 barrier/chunk;
// next chunk's att-build (global loads) overlaps current chunk's MFMAs.
__global__ __launch_bounds__(256) void k_hprime(const float* __restrict__ e,
                                                const ushort* __restrict__ adjp,
                                                const ushort* __restrict__ hT_bf,
                                                const float* __restrict__ cm1, const float* __restrict__ cs1,
                                                const float* __restrict__ cm2, const float* __restrict__ cs2,
                                                float* __restrict__ hp1, float* __restrict__ hp2) {
    __shared__ ushort s_att[2][2][16 * 40];   // [buf][path][row*40+j]
    __shared__ float s_st[4][NN];             // cm1, cs1, cm2, cs2
    int b = blockIdx.y, i0 = blockIdx.x * 16;
    int tid = threadIdx.x;
    int w = tid >> 6, l = tid & 63;
    int path = w >> 1, half = w & 1;
    int ntbase = half * 5, ncnt = half ? 4 : 5;
    int lr = l & 15, kg = l >> 4;
    for (int idx = tid; idx < NN; idx += 256) {
        s_st[0][idx] = cm1[b * NN + idx];
        s_st[1][idx] = cs1[b * NN + idx];
        s_st[2][idx] = cm2[b * NN + idx];
        s_st[3][idx] = cs2[b * NN + idx];
    }
    int ai = tid >> 4, aj2 = (tid & 15) * 2;
    const float* e_row = e + (size_t)b * NN * NN + (size_t)(i0 + ai) * NN;
    const ushort* p_row = adjp + (size_t)b * NN * NN + (size_t)(i0 + ai) * NN;
    const ushort* hTb = hT_bf + (size_t)b * DP * NN;

    auto build = [&](int c, int buf) {
        int j = c * 32 + aj2;
        float2 ev = *reinterpret_cast<const float2*>(e_row + j);
        uint pv = *reinterpret_cast<const uint*>(p_row + j);
        float evv[2] = {ev.x, ev.y};
        ushort hbits[2] = {(ushort)(pv & 0xFFFFu), (ushort)(pv >> 16)};
        ushort o1[2], o2[2];
#pragma unroll
        for (int c2 = 0; c2 < 2; ++c2) {
            int jj = j + c2;
            bool mask = (hbits[c2] & 0x8000u) != 0;
            float a2 = h2f_bits((ushort)(hbits[c2] & 0x7FFFu));
            float att1 = mask ? __expf(evv[c2] - s_st[0][jj]) * s_st[1][jj] : 0.f;
            float att2 = a2 * __expf(evv[c2] - s_st[2][jj]) * s_st[3][jj];
            o1[c2] = f2bf(att1); o2[c2] = f2bf(att2);
        }
        *reinterpret_cast<uint*>(&s_att[buf][0][ai * 40 + aj2]) = (uint)o1[0] | ((uint)o1[1] << 16);
        *reinterpret_cast<uint*>(&s_att[buf][1][ai * 40 + aj2]) = (uint)o2[0] | ((uint)o2[1] << 16);
    };

    f32x4 acc[5];
#pragma unroll
    for (int nt = 0; nt < 5; ++nt) acc[nt] = (f32x4)(0.f);

    build(0, 0);
    __syncthreads();
    for (int c = 0; c < 16; ++c) {
        int cb = c & 1, nb = cb ^ 1;
        if (c < 15) build(c + 1, nb);
        int j0 = c * 32;
        bf16x8 afr = *reinterpret_cast<const bf16x8*>(&s_att[cb][path][lr * 40 + kg * 8]);
#pragma unroll
        for (int nt = 0; nt < 5; ++nt) {
            if (nt < ncnt) {
                bf16x8 bfr = *reinterpret_cast<const bf16x8*>(
                    hTb + (size_t)((ntbase + nt) * 16 + lr) * NN + j0 + kg * 8);
                acc[nt] = __builtin_amdgcn_mfma_f32_16x16x32_bf16(afr, bfr, acc[nt], 0, 0, 0);
            }
        }
        __syncthreads();
    }
    float* hp = path ? hp2 : hp1;
    int rbase = i0 + kg * 4;
#pragma unroll
    for (int nt = 0; nt < 5; ++nt) {
        if (nt < ncnt) {
            int col = (ntbase + nt) * 16 + lr;
            if (col < DD) {
#pragma unroll
                for (int r = 0; r < 4; ++r)
                    hp[(size_t)b * NN * DD + (size_t)(rbase + r) * DD + col] = fmaxf(acc[nt][r], 0.f);
            }
        }
    }
}

// ---------------------------------------------------------------------------
// gate + layer update: x = gate(x,hp2) - gate(x,hp1); also refresh x_bf.
__global__ __launch_bounds__(64) void k_gate(const float* __restrict__ hp1,
                                             const float* __restrict__ hp2,
                                             const float* __restrict__ gw,
                                             const float* __restrict__ gb,
                                             float* __restrict__ x,
                                             ushort* __restrict__ x_bf) {
    int bn = blockIdx.x;
    int t = threadIdx.x;
    const float* xr = x + (size_t)bn * DD;
    const float* h1r = hp1 + (size_t)bn * DD;
    const float* h2r = hp2 + (size_t)bn * DD;
    float xv[3], h1v[3], h2v[3];
    float sx = 0.f, s1 = 0.f, s2 = 0.f;
#pragma unroll
    for (int q = 0; q < 3; ++q) {
        int dd2 = t + 64 * q;
        bool ok = dd2 < DD;
        xv[q]  = ok ? xr[dd2]  : 0.f;
        h1v[q] = ok ? h1r[dd2] : 0.f;
        h2v[q] = ok ? h2r[dd2] : 0.f;
        float gl = ok ? gw[dd2] : 0.f;
        float gh = ok ? gw[DD + dd2] : 0.f;
        sx = fmaf(xv[q], gl, sx);
        s1 = fmaf(h1v[q], gh, s1);
        s2 = fmaf(h2v[q], gh, s2);
    }
#pragma unroll
    for (int off = 32; off > 0; off >>= 1) {
        sx += __shfl_down(sx, off);
        s1 += __shfl_down(s1, off);
        s2 += __shfl_down(s2, off);
    }
    float z1 = __shfl(sx + s1, 0);
    float z2 = __shfl(sx + s2, 0);
    float gbv = gb[0];
    float c1 = 1.f / (1.f + __expf(-(z1 + gbv)));
    float c2 = 1.f / (1.f + __expf(-(z2 + gbv)));
#pragma unroll
    for (int q = 0; q < 3; ++q) {
        int dd2 = t + 64 * q;
        if (dd2 < DD) {
            float xnew = (c2 - c1) * xv[q] + (1.f - c2) * h2v[q] - (1.f - c1) * h1v[q];
            x[(size_t)bn * DD + dd2] = xnew;
            x_bf[(size_t)bn * DP + dd2] = f2bf(xnew);
        }
    }
}

// ---------------------------------------------------------------------------
// readout: g[b,d] = sum_n x[b,n,d] * valid[b,n]
__global__ __launch_bounds__(256) void k_readout(const float* __restrict__ x,
                                                 const float* __restrict__ valid,
                                                 float* __restrict__ g) {
    int b = blockIdx.x;
    int t = threadIdx.x;
    if (t < DD) {
        float acc = 0.f;
        for (int n = 0; n < NN; ++n)
            acc = fmaf(x[((size_t)b * NN + n) * DD + t], valid[b * NN + n], acc);
        g[b * DD + t] = acc;
    }
}

// ---------------------------------------------------------------------------
// tiny MLP head: relu x3 + sigmoid
__global__ __launch_bounds__(128) void k_mlp(const float* __restrict__ g,
                                             const float* __restrict__ w0, const float* __restrict__ b0,
                                             const float* __restrict__ w1, const float* __restrict__ b1,
                                             const float* __restrict__ w2, const float* __restrict__ b2,
                                             const float* __restrict__ w3, const float* __restrict__ b3,
                                             float* __restrict__ out) {
    __shared__ float s0[DD];
    __shared__ float s1[DF];
    __shared__ float s2[DF];
    __shared__ float s_part[2];
    int b = blockIdx.x, t = threadIdx.x;
    for (int i = t; i < DD; i += 128) s0[i] = g[b * DD + i];
    __syncthreads();
    float acc = b0[t];
    for (int dd2 = 0; dd2 < DD; ++dd2) acc = fmaf(s0[dd2], w0[dd2 * DF + t], acc);
    s1[t] = fmaxf(acc, 0.f);
    __syncthreads();
    acc = b1[t];
    for (int dd2 = 0; dd2 < DF; ++dd2) acc = fmaf(s1[dd2], w1[dd2 * DF + t], acc);
    s2[t] = fmaxf(acc, 0.f);
    __syncthreads();
    acc = b2[t];
    for (int dd2 = 0; dd2 < DF; ++dd2) acc = fmaf(s2[dd2], w2[dd2 * DF + t], acc);
    float h3 = fmaxf(acc, 0.f);
    float p = h3 * w3[t];
#pragma unroll
    for (int off = 32; off > 0; off >>= 1) p += __shfl_down(p, off);
    if ((t & 63) == 0) s_part[t >> 6] = p;
    __syncthreads();
    if (t == 0) {
        float s = s_part[0] + s_part[1] + b3[0];
        out[b] = 1.f / (1.f + __expf(-s));
    }
}

// ---------------------------------------------------------------------------
extern "C" void kernel_launch(void* const* d_in, const int* in_sizes, int n_in,
                              void* d_out, int out_size, void* d_ws, size_t ws_size,
                              hipStream_t stream) {
    const float* chs   = (const float*)d_in[0];
    const float* adj1  = (const float*)d_in[1];
    const float* dist  = (const float*)d_in[2];
    const float* valid = (const float*)d_in[3];
    const float* We    = (const float*)d_in[4];
    const float* Ww    = (const float*)d_in[5];
    const float* Wb    = (const float*)d_in[6];
    const float* A     = (const float*)d_in[7];
    const float* gw    = (const float*)d_in[8];
    const float* gb    = (const float*)d_in[9];
    const float* mu    = (const float*)d_in[10];
    const float* dev   = (const float*)d_in[11];
    const float* w0    = (const float*)d_in[12];
    const float* b0    = (const float*)d_in[13];
    const float* w1    = (const float*)d_in[14];
    const float* b1    = (const float*)d_in[15];
    const float* w2    = (const float*)d_in[16];
    const float* b2    = (const float*)d_in[17];
    const float* w3    = (const float*)d_in[18];
    const float* b3    = (const float*)d_in[19];
    float* out = (float*)d_out;

    const size_t SX  = (size_t)BB * NN * DD;
    const size_t SNN = (size_t)BB * NN * NN;
    const size_t SBF = (size_t)BB * NN * DP;
    float* ws  = (float*)d_ws;
    float* x   = ws;
    float* hp1 = x + SX;
    float* hp2 = hp1 + SX;
    float* e   = hp2 + SX;
    float* cm1 = e + SNN;
    float* cs1 = cm1 + BB * NN;
    float* cm2 = cs1 + BB * NN;
    float* cs2 = cm2 + BB * NN;
    float* g   = cs2 + BB * NN;
    ushort* h_bf  = (ushort*)(g + BB * DD);
    ushort* hA_bf = h_bf + SBF;
    ushort* hT_bf = hA_bf + SBF;
    ushort* x_bf  = hT_bf + SBF;
    ushort* Wwb   = x_bf + SBF;
    ushort* ATb   = Wwb + (size_t)LL * DP * DP;
    ushort* adjp  = ATb + (size_t)LL * DP * DP;   // BB*NN*NN fp16 (signed)

    k_prepa<<<SNN / 1024, 256, 0, stream>>>(adj1, dist, mu, dev, adjp);
    k_prepw<<<dim3(DP * DP / 256, LL), 256, 0, stream>>>(Ww, A, Wwb, ATb);
    k_embed<<<BB * NN / 32, 256, 0, stream>>>(chs, We, x, x_bf);

    for (int k = 0; k < LL; ++k) {
        const ushort* Wwbk = Wwb + (size_t)k * DP * DP;
        const ushort* ATbk = ATb + (size_t)k * DP * DP;
        const float* Wbk = Wb + (size_t)k * DD;
        const float* gwk = gw + (size_t)k * 2 * DD;
        const float* gbk = gb + k;
        k_wtrans<<<BB * NN / 32, 256, 0, stream>>>(x_bf, Wwbk, ATbk, Wbk, h_bf, hA_bf, hT_bf);
        k_esym<<<dim3(NN / 64, NN / 64, BB), 256, 0, stream>>>(h_bf, hA_bf, e);
        k_colsm<<<dim3(NN / 4, BB), 256, 0, stream>>>(e, adjp, cm1, cs1, cm2, cs2);
        k_hprime<<<dim3(NN / 16, BB), 256, 0, stream>>>(e, adjp, hT_bf,
                                                        cm1, cs1, cm2, cs2, hp1, hp2);
        k_gate<<<BB * NN, 64, 0, stream>>>(hp1, hp2, gwk, gbk, x, x_bf);
    }

    k_readout<<<BB, 256, 0, stream>>>(x, valid, g);
    k_mlp<<<BB, 128, 0, stream>>>(g, w0, b0, w1, b1, w2, b2, w3, b3, out);
}

// Round 6
// 490.357 us; speedup vs baseline: 5.4516x; 1.0477x over previous
//
#include <hip/hip_runtime.h>
#include <hip/hip_fp16.h>

#define BB 32
#define NN 512
#define FIN 74
#define DD 140
#define DP 160            // padded d (zero-filled 140..159), multiple of 32
#define DF 128
#define LL 4
#define NEGV (-9e15f)
#define RST 148           // s_red stride (floats): 148%32=20 -> 2-way banks

typedef __attribute__((ext_vector_type(8))) short bf16x8;
typedef __attribute__((ext_vector_type(4))) float f32x4;

__device__ inline ushort f2bf(float x) {
    union { float f; unsigned u; } v; v.f = x;
    unsigned r = (v.u + 0x7FFFu + ((v.u >> 16) & 1u)) >> 16;   // RNE
    return (ushort)r;
}
__device__ inline ushort f2h_bits(float x) {
    __half h = __float2half(x);
    union { __half h; ushort u; } c; c.h = h; return c.u;
}
__device__ inline float h2f_bits(ushort u) {
    union { __half h; ushort u; } c; c.u = u; return __half2float(c.h);
}

// ---------------------------------------------------------------------------
// prep adjacency: adjp[b,i,j] = fp16(exp(-(dist-mu)^2/dev) + a1), sign bit =
// (a1>0). a1 is exactly 0/1; exp term >= e^-16 ~ 1.1e-7 > fp16 min subnormal.
__global__ __launch_bounds__(256) void k_prepa(const float* __restrict__ adj1,
                                               const float* __restrict__ dist,
                                               const float* __restrict__ mu_p,
                                               const float* __restrict__ dev_p,
                                               ushort* __restrict__ adjp) {
    float mu = mu_p[0], rdev = 1.0f / dev_p[0];
    size_t base = ((size_t)blockIdx.x * 256 + threadIdx.x) * 4;
    float4 av = *reinterpret_cast<const float4*>(adj1 + base);
    float4 dv = *reinterpret_cast<const float4*>(dist + base);
    float aa[4] = {av.x, av.y, av.z, av.w};
    float dd[4] = {dv.x, dv.y, dv.z, dv.w};
    ushort o[4];
#pragma unroll
    for (int c = 0; c < 4; ++c) {
        float t = dd[c] - mu;
        float a2 = __expf(-t * t * rdev) + aa[c];
        ushort h = f2h_bits(a2);
        if (aa[c] > 0.f) h |= 0x8000u;
        o[c] = h;
    }
    uint2 pk;
    pk.x = (uint)o[0] | ((uint)o[1] << 16);
    pk.y = (uint)o[2] | ((uint)o[3] << 16);
    *reinterpret_cast<uint2*>(adjp + base) = pk;
}

// ---------------------------------------------------------------------------
// prep weights: Wwb[k][d][f] = bf16(Ww[k][d][f]) padded; ATb[k][d][d2] =
// bf16(A[k][d2][d]) padded (transposed for contiguous B-frag reads).
__global__ __launch_bounds__(256) void k_prepw(const float* __restrict__ Ww,
                                               const float* __restrict__ A,
                                               ushort* __restrict__ Wwb,
                                               ushort* __restrict__ ATb) {
    int k = blockIdx.y;
    int idx = blockIdx.x * 256 + threadIdx.x;     // over DP*DP = 25600
    int d = idx / DP, f = idx % DP;
    const float* Wk = Ww + (size_t)k * DD * DD;
    const float* Ak = A + (size_t)k * DD * DD;
    ushort wv = 0, av = 0;
    if (d < DD && f < DD) {
        wv = f2bf(Wk[d * DD + f]);
        av = f2bf(Ak[f * DD + d]);
    }
    Wwb[(size_t)k * DP * DP + idx] = wv;
    ATb[(size_t)k * DP * DP + idx] = av;
}

// ---------------------------------------------------------------------------
// embed: x[b,n,d] = sum_f c_hs[b,n,f] * We[d,f]; also emits x_bf (padded).
__global__ __launch_bounds__(256) void k_embed(const float* __restrict__ chs,
                                               const float* __restrict__ We,
                                               float* __restrict__ x,
                                               ushort* __restrict__ x_bf) {
    __shared__ float s_we[FIN * 144];
    __shared__ float s_in[32 * FIN];
    int bn0 = blockIdx.x * 32;
    int tid = threadIdx.x;
    for (int idx = tid; idx < DD * FIN; idx += 256) {
        int r = idx / FIN, c = idx % FIN;
        s_we[c * 144 + r] = We[idx];
    }
    for (int idx = tid; idx < 32 * FIN; idx += 256)
        s_in[idx] = chs[(size_t)bn0 * FIN + idx];
    __syncthreads();
    int d = tid;
    if (d < DD) {
        float acc[32];
#pragma unroll
        for (int r = 0; r < 32; ++r) acc[r] = 0.f;
        for (int f = 0; f < FIN; ++f) {
            float w = s_we[f * 144 + d];
#pragma unroll
            for (int r = 0; r < 32; ++r) acc[r] = fmaf(s_in[r * FIN + f], w, acc[r]);
        }
#pragma unroll
        for (int r = 0; r < 32; ++r) {
            x[(size_t)(bn0 + r) * DD + d] = acc[r];
            x_bf[(size_t)(bn0 + r) * DP + d] = f2bf(acc[r]);
        }
    } else if (d < DP) {
#pragma unroll
        for (int r = 0; r < 32; ++r) x_bf[(size_t)(bn0 + r) * DP + d] = 0;
    }
}

// ---------------------------------------------------------------------------
// wtrans via MFMA: h = x@Ww^T + Wb ; hA = h@A.
__global__ __launch_bounds__(256) void k_wtrans(const ushort* __restrict__ x_bf,
                                                const ushort* __restrict__ Wwb,
                                                const ushort* __restrict__ ATb,
                                                const float* __restrict__ Wb,
                                                ushort* __restrict__ h_bf,
                                                ushort* __restrict__ hA_bf,
                                                ushort* __restrict__ hT_bf) {
    __shared__ __align__(16) ushort s_h[32][168];
    int bn0 = blockIdx.x * 32;
    int b = bn0 >> 9, n0 = bn0 & (NN - 1);
    int tid = threadIdx.x;
    int w = tid >> 6, l = tid & 63;
    int wm = w & 1, wc = w >> 1;
    int lr = l & 15, kg = l >> 4;
    const ushort* xrow = x_bf + (size_t)(bn0 + wm * 16 + lr) * DP;
    f32x4 acc[5];
#pragma unroll
    for (int nt = 0; nt < 5; ++nt) acc[nt] = (f32x4)(0.f);
    for (int f0 = 0; f0 < DP; f0 += 32) {
        bf16x8 a = *reinterpret_cast<const bf16x8*>(xrow + f0 + kg * 8);
#pragma unroll
        for (int nt = 0; nt < 5; ++nt) {
            int col = (wc * 5 + nt) * 16 + lr;
            bf16x8 bfr = *reinterpret_cast<const bf16x8*>(Wwb + (size_t)col * DP + f0 + kg * 8);
            acc[nt] = __builtin_amdgcn_mfma_f32_16x16x32_bf16(a, bfr, acc[nt], 0, 0, 0);
        }
    }
#pragma unroll
    for (int nt = 0; nt < 5; ++nt) {
        int col = (wc * 5 + nt) * 16 + lr;
        float bias = col < DD ? Wb[col] : 0.f;
#pragma unroll
        for (int r = 0; r < 4; ++r) {
            int rowl = wm * 16 + kg * 4 + r;
            float v = col < DD ? acc[nt][r] + bias : 0.f;
            ushort u = f2bf(v);
            s_h[rowl][col] = u;
            h_bf[(size_t)(bn0 + rowl) * DP + col] = u;
        }
        acc[nt] = (f32x4)(0.f);
    }
    __syncthreads();
    for (int f0 = 0; f0 < DP; f0 += 32) {
        bf16x8 a = *reinterpret_cast<const bf16x8*>(&s_h[wm * 16 + lr][f0 + kg * 8]);
#pragma unroll
        for (int nt = 0; nt < 5; ++nt) {
            int col = (wc * 5 + nt) * 16 + lr;
            bf16x8 bfr = *reinterpret_cast<const bf16x8*>(ATb + (size_t)col * DP + f0 + kg * 8);
            acc[nt] = __builtin_amdgcn_mfma_f32_16x16x32_bf16(a, bfr, acc[nt], 0, 0, 0);
        }
    }
#pragma unroll
    for (int nt = 0; nt < 5; ++nt) {
        int col = (wc * 5 + nt) * 16 + lr;
#pragma unroll
        for (int r = 0; r < 4; ++r)
            hA_bf[(size_t)(bn0 + wm * 16 + kg * 4 + r) * DP + col] = f2bf(acc[nt][r]);
    }
    if (tid < DP) {
        int d = tid;
        ushort tmp[32];
#pragma unroll
        for (int nn = 0; nn < 32; ++nn) tmp[nn] = s_h[nn][d];
        ushort* dst = hT_bf + ((size_t)b * DP + d) * NN + n0;
#pragma unroll
        for (int q = 0; q < 4; ++q)
            *reinterpret_cast<bf16x8*>(dst + q * 8) = *reinterpret_cast<const bf16x8*>(tmp + q * 8);
    }
}

// ---------------------------------------------------------------------------
// esym via MFMA: e[i][j] = hA_i·h_j + h_i·hA_j.
__global__ __launch_bounds__(256) void k_esym(const ushort* __restrict__ h_bf,
                                              const ushort* __restrict__ hA_bf,
                                              float* __restrict__ e) {
    int b = blockIdx.z;
    int i0 = blockIdx.y * 64, j0 = blockIdx.x * 64;
    int w = threadIdx.x >> 6, l = threadIdx.x & 63;
    int wm = w & 1, wn = w >> 1;
    int lr = l & 15, kg = l >> 4;
    const ushort* hb = h_bf + (size_t)b * NN * DP;
    const ushort* ab = hA_bf + (size_t)b * NN * DP;
    f32x4 acc[2][2];
#pragma unroll
    for (int mt = 0; mt < 2; ++mt)
#pragma unroll
        for (int nt = 0; nt < 2; ++nt) acc[mt][nt] = (f32x4)(0.f);
    size_t moff[2], noff[2];
#pragma unroll
    for (int t = 0; t < 2; ++t) {
        moff[t] = (size_t)(i0 + wm * 32 + t * 16 + lr) * DP;
        noff[t] = (size_t)(j0 + wn * 32 + t * 16 + lr) * DP;
    }
    for (int d0 = 0; d0 < DP; d0 += 32) {
        int off = d0 + kg * 8;
        bf16x8 am[2], hm[2], hn[2], an[2];
#pragma unroll
        for (int t = 0; t < 2; ++t) {
            am[t] = *reinterpret_cast<const bf16x8*>(ab + moff[t] + off);
            hm[t] = *reinterpret_cast<const bf16x8*>(hb + moff[t] + off);
            hn[t] = *reinterpret_cast<const bf16x8*>(hb + noff[t] + off);
            an[t] = *reinterpret_cast<const bf16x8*>(ab + noff[t] + off);
        }
#pragma unroll
        for (int mt = 0; mt < 2; ++mt)
#pragma unroll
            for (int nt = 0; nt < 2; ++nt) {
                acc[mt][nt] = __builtin_amdgcn_mfma_f32_16x16x32_bf16(am[mt], hn[nt], acc[mt][nt], 0, 0, 0);
                acc[mt][nt] = __builtin_amdgcn_mfma_f32_16x16x32_bf16(hm[mt], an[nt], acc[mt][nt], 0, 0, 0);
            }
    }
    float* eb = e + (size_t)b * NN * NN;
#pragma unroll
    for (int mt = 0; mt < 2; ++mt) {
        int rbase = i0 + wm * 32 + mt * 16 + kg * 4;
#pragma unroll
        for (int nt = 0; nt < 2; ++nt) {
            int col = j0 + wn * 32 + nt * 16 + lr;
#pragma unroll
            for (int r = 0; r < 4; ++r)
                eb[(size_t)(rbase + r) * NN + col] = acc[mt][nt][r];
        }
    }
}

// ---------------------------------------------------------------------------
// column-softmax stats (== row stats by symmetry). One wave per (b,j).
// Outputs single float per path: C = m + log(s); att = exp(e - C).
__global__ __launch_bounds__(256) void k_colsm(const float* __restrict__ e,
                                               const ushort* __restrict__ adjp,
                                               float* __restrict__ C1, float* __restrict__ C2) {
    int b = blockIdx.y;
    int j = blockIdx.x * 4 + (threadIdx.x >> 6);
    int lane = threadIdx.x & 63;
    const float4* e4 = reinterpret_cast<const float4*>(e + ((size_t)b * NN + j) * NN);
    const uint2* p4 = reinterpret_cast<const uint2*>(adjp + ((size_t)b * NN + j) * NN);
    float v1[8], v2[8];
#pragma unroll
    for (int it = 0; it < 2; ++it) {
        float4 ev = e4[lane + 64 * it];
        uint2 pv = p4[lane + 64 * it];
        float evv[4] = {ev.x, ev.y, ev.z, ev.w};
        uint mk[4] = {pv.x & 0x8000u, pv.x & 0x80000000u, pv.y & 0x8000u, pv.y & 0x80000000u};
#pragma unroll
        for (int c = 0; c < 4; ++c) {
            v2[it * 4 + c] = evv[c];
            v1[it * 4 + c] = mk[c] ? evv[c] : NEGV;
        }
    }
    float m1 = v1[0], m2 = v2[0];
#pragma unroll
    for (int q = 1; q < 8; ++q) { m1 = fmaxf(m1, v1[q]); m2 = fmaxf(m2, v2[q]); }
    float s1 = 0.f, s2 = 0.f;
#pragma unroll
    for (int q = 0; q < 8; ++q) { s1 += __expf(v1[q] - m1); s2 += __expf(v2[q] - m2); }
#pragma unroll
    for (int off = 1; off < 64; off <<= 1) {
        float mo1 = __shfl_xor(m1, off), so1 = __shfl_xor(s1, off);
        float mo2 = __shfl_xor(m2, off), so2 = __shfl_xor(s2, off);
        float mn1 = fmaxf(m1, mo1);
        s1 = s1 * __expf(m1 - mn1) + so1 * __expf(mo1 - mn1);
        m1 = mn1;
        float mn2 = fmaxf(m2, mo2);
        s2 = s2 * __expf(m2 - mn2) + so2 * __expf(mo2 - mn2);
        m2 = mn2;
    }
    if (lane == 0) {
        C1[b * NN + j] = m1 + __logf(s1);
        C2[b * NN + j] = m2 + __logf(s2);
    }
}

// ---------------------------------------------------------------------------
// hprime + gate, fused. Per block: 16 i-rows of one batch. 4 waves =
// (path p x j-half s). Barrier-free inner loop: each lane builds its own
// MFMA A-frag (att[i0+lr][jl..jl+8]) from global e/adjp in registers.
// LDS reduction merges j-halves, then gate applied in-block; x/x_bf updated.
__global__ __launch_bounds__(256) void k_hprime(const float* __restrict__ e,
                                                const ushort* __restrict__ adjp,
                                                const ushort* __restrict__ hT_bf,
                                                const float* __restrict__ C1,
                                                const float* __restrict__ C2,
                                                const float* __restrict__ gw,
                                                const float* __restrict__ gb,
                                                float* __restrict__ x,
                                                ushort* __restrict__ x_bf) {
    __shared__ float s_C[2][NN];                       // 4 KB
    __shared__ float s_red[2][16][RST];                // 2*16*148*4 = 18.9 KB
    int b = blockIdx.y, i0 = blockIdx.x * 16;
    int tid = threadIdx.x;
    int w = tid >> 6, l = tid & 63;
    int p = w >> 1, s = w & 1;
    int lr = l & 15, kg = l >> 4;
    for (int idx = tid; idx < NN; idx += 256) {
        s_C[0][idx] = C1[b * NN + idx];
        s_C[1][idx] = C2[b * NN + idx];
    }
    __syncthreads();
    const float* e_row = e + (size_t)b * NN * NN + (size_t)(i0 + lr) * NN;
    const ushort* p_row = adjp + (size_t)b * NN * NN + (size_t)(i0 + lr) * NN;
    const ushort* hTb = hT_bf + (size_t)b * DP * NN;
    f32x4 acc[9];
#pragma unroll
    for (int nt = 0; nt < 9; ++nt) acc[nt] = (f32x4)(0.f);

    for (int c = 0; c < 8; ++c) {
        int jl = s * 256 + c * 32 + kg * 8;
        float4 e0 = *reinterpret_cast<const float4*>(e_row + jl);
        float4 e1 = *reinterpret_cast<const float4*>(e_row + jl + 4);
        uint4 pv = *reinterpret_cast<const uint4*>(p_row + jl);
        float ev[8] = {e0.x, e0.y, e0.z, e0.w, e1.x, e1.y, e1.z, e1.w};
        ushort hb[8] = {(ushort)(pv.x & 0xFFFFu), (ushort)(pv.x >> 16),
                        (ushort)(pv.y & 0xFFFFu), (ushort)(pv.y >> 16),
                        (ushort)(pv.z & 0xFFFFu), (ushort)(pv.z >> 16),
                        (ushort)(pv.w & 0xFFFFu), (ushort)(pv.w >> 16)};
        ushort o[8];
        if (p == 0) {
#pragma unroll
            for (int q = 0; q < 8; ++q) {
                float t = __expf(ev[q] - s_C[0][jl + q]);
                o[q] = (hb[q] & 0x8000u) ? f2bf(t) : (ushort)0;
            }
        } else {
#pragma unroll
            for (int q = 0; q < 8; ++q) {
                float a2 = h2f_bits((ushort)(hb[q] & 0x7FFFu));
                o[q] = f2bf(a2 * __expf(ev[q] - s_C[1][jl + q]));
            }
        }
        union { ushort u[8]; bf16x8 v; } afr;
#pragma unroll
        for (int q = 0; q < 8; ++q) afr.u[q] = o[q];
#pragma unroll
        for (int nt = 0; nt < 9; ++nt) {
            bf16x8 bfr = *reinterpret_cast<const bf16x8*>(hTb + (size_t)(nt * 16 + lr) * NN + jl);
            acc[nt] = __builtin_amdgcn_mfma_f32_16x16x32_bf16(afr.v, bfr, acc[nt], 0, 0, 0);
        }
    }
    // merge j-halves: s==1 writes partial, s==0 adds + relu
    if (s == 1) {
#pragma unroll
        for (int nt = 0; nt < 9; ++nt)
#pragma unroll
            for (int r = 0; r < 4; ++r)
                s_red[p][kg * 4 + r][nt * 16 + lr] = acc[nt][r];
    }
    __syncthreads();
    if (s == 0) {
#pragma unroll
        for (int nt = 0; nt < 9; ++nt)
#pragma unroll
            for (int r = 0; r < 4; ++r) {
                float v = acc[nt][r] + s_red[p][kg * 4 + r][nt * 16 + lr];
                s_red[p][kg * 4 + r][nt * 16 + lr] = fmaxf(v, 0.f);
            }
    }
    __syncthreads();
    // gate: 4 waves x 4 rows, 16 lanes per row
    int row = w * 4 + (l >> 4);
    int dl = l & 15;
    int bn = b * NN + i0 + row;
    const float* xr = x + (size_t)bn * DD;
    float xv[9], h1v[9], h2v[9];
    float sx = 0.f, s1 = 0.f, s2 = 0.f;
#pragma unroll
    for (int q = 0; q < 9; ++q) {
        int d = dl + q * 16;
        bool ok = d < DD;
        float xd = ok ? xr[d] : 0.f;
        float g0 = ok ? gw[d] : 0.f;
        float g1 = ok ? gw[DD + d] : 0.f;
        float h1 = ok ? s_red[0][row][d] : 0.f;
        float h2 = ok ? s_red[1][row][d] : 0.f;
        xv[q] = xd; h1v[q] = h1; h2v[q] = h2;
        sx = fmaf(xd, g0, sx);
        s1 = fmaf(h1, g1, s1);
        s2 = fmaf(h2, g1, s2);
    }
#pragma unroll
    for (int off = 1; off < 16; off <<= 1) {
        sx += __shfl_xor(sx, off);
        s1 += __shfl_xor(s1, off);
        s2 += __shfl_xor(s2, off);
    }
    float gbv = gb[0];
    float c1 = 1.f / (1.f + __expf(-(sx + s1 + gbv)));
    float c2 = 1.f / (1.f + __expf(-(sx + s2 + gbv)));
#pragma unroll
    for (int q = 0; q < 9; ++q) {
        int d = dl + q * 16;
        if (d < DD) {
            float xnew = (c2 - c1) * xv[q] + (1.f - c2) * h2v[q] - (1.f - c1) * h1v[q];
            x[(size_t)bn * DD + d] = xnew;
            x_bf[(size_t)bn * DP + d] = f2bf(xnew);
        }
    }
}

// ---------------------------------------------------------------------------
// readout: g[b,d] = sum_n x[b,n,d] * valid[b,n]
__global__ __launch_bounds__(256) void k_readout(const float* __restrict__ x,
                                                 const float* __restrict__ valid,
                                                 float* __restrict__ g) {
    int b = blockIdx.x;
    int t = threadIdx.x;
    if (t < DD) {
        float acc = 0.f;
        for (int n = 0; n < NN; ++n)
            acc = fmaf(x[((size_t)b * NN + n) * DD + t], valid[b * NN + n], acc);
        g[b * DD + t] = acc;
    }
}

// ---------------------------------------------------------------------------
// tiny MLP head: relu x3 + sigmoid
__global__ __launch_bounds__(128) void k_mlp(const float* __restrict__ g,
                                             const float* __restrict__ w0, const float* __restrict__ b0,
                                             const float* __restrict__ w1, const float* __restrict__ b1,
                                             const float* __restrict__ w2, const float* __restrict__ b2,
                                             const float* __restrict__ w3, const float* __restrict__ b3,
                                             float* __restrict__ out) {
    __shared__ float s0[DD];
    __shared__ float s1[DF];
    __shared__ float s2[DF];
    __shared__ float s_part[2];
    int b = blockIdx.x, t = threadIdx.x;
    for (int i = t; i < DD; i += 128) s0[i] = g[b * DD + i];
    __syncthreads();
    float acc = b0[t];
    for (int dd2 = 0; dd2 < DD; ++dd2) acc = fmaf(s0[dd2], w0[dd2 * DF + t], acc);
    s1[t] = fmaxf(acc, 0.f);
    __syncthreads();
    acc = b1[t];
    for (int dd2 = 0; dd2 < DF; ++dd2) acc = fmaf(s1[dd2], w1[dd2 * DF + t], acc);
    s2[t] = fmaxf(acc, 0.f);
    __syncthreads();
    acc = b2[t];
    for (int dd2 = 0; dd2 < DF; ++dd2) acc = fmaf(s2[dd2], w2[dd2 * DF + t], acc);
    float h3 = fmaxf(acc, 0.f);
    float p = h3 * w3[t];
#pragma unroll
    for (int off = 32; off > 0; off >>= 1) p += __shfl_down(p, off);
    if ((t & 63) == 0) s_part[t >> 6] = p;
    __syncthreads();
    if (t == 0) {
        float s = s_part[0] + s_part[1] + b3[0];
        out[b] = 1.f / (1.f + __expf(-s));
    }
}

// ---------------------------------------------------------------------------
extern "C" void kernel_launch(void* const* d_in, const int* in_sizes, int n_in,
                              void* d_out, int out_size, void* d_ws, size_t ws_size,
                              hipStream_t stream) {
    const float* chs   = (const float*)d_in[0];
    const float* adj1  = (const float*)d_in[1];
    const float* dist  = (const float*)d_in[2];
    const float* valid = (const float*)d_in[3];
    const float* We    = (const float*)d_in[4];
    const float* Ww    = (const float*)d_in[5];
    const float* Wb    = (const float*)d_in[6];
    const float* A     = (const float*)d_in[7];
    const float* gw    = (const float*)d_in[8];
    const float* gb    = (const float*)d_in[9];
    const float* mu    = (const float*)d_in[10];
    const float* dev   = (const float*)d_in[11];
    const float* w0    = (const float*)d_in[12];
    const float* b0    = (const float*)d_in[13];
    const float* w1    = (const float*)d_in[14];
    const float* b1    = (const float*)d_in[15];
    const float* w2    = (const float*)d_in[16];
    const float* b2    = (const float*)d_in[17];
    const float* w3    = (const float*)d_in[18];
    const float* b3    = (const float*)d_in[19];
    float* out = (float*)d_out;

    const size_t SX  = (size_t)BB * NN * DD;
    const size_t SNN = (size_t)BB * NN * NN;
    const size_t SBF = (size_t)BB * NN * DP;
    float* ws  = (float*)d_ws;
    float* x   = ws;
    float* e   = x + SX;
    float* C1  = e + SNN;
    float* C2  = C1 + BB * NN;
    float* g   = C2 + BB * NN;
    ushort* h_bf  = (ushort*)(g + BB * DD);
    ushort* hA_bf = h_bf + SBF;
    ushort* hT_bf = hA_bf + SBF;
    ushort* x_bf  = hT_bf + SBF;
    ushort* Wwb   = x_bf + SBF;
    ushort* ATb   = Wwb + (size_t)LL * DP * DP;
    ushort* adjp  = ATb + (size_t)LL * DP * DP;   // BB*NN*NN fp16 (signed)

    k_prepa<<<SNN / 1024, 256, 0, stream>>>(adj1, dist, mu, dev, adjp);
    k_prepw<<<dim3(DP * DP / 256, LL), 256, 0, stream>>>(Ww, A, Wwb, ATb);
    k_embed<<<BB * NN / 32, 256, 0, stream>>>(chs, We, x, x_bf);

    for (int k = 0; k < LL; ++k) {
        const ushort* Wwbk = Wwb + (size_t)k * DP * DP;
        const ushort* ATbk = ATb + (size_t)k * DP * DP;
        const float* Wbk = Wb + (size_t)k * DD;
        const float* gwk = gw + (size_t)k * 2 * DD;
        const float* gbk = gb + k;
        k_wtrans<<<BB * NN / 32, 256, 0, stream>>>(x_bf, Wwbk, ATbk, Wbk, h_bf, hA_bf, hT_bf);
        k_esym<<<dim3(NN / 64, NN / 64, BB), 256, 0, stream>>>(h_bf, hA_bf, e);
        k_colsm<<<dim3(NN / 4, BB), 256, 0, stream>>>(e, adjp, C1, C2);
        k_hprime<<<dim3(NN / 16, BB), 256, 0, stream>>>(e, adjp, hT_bf, C1, C2,
                                                        gwk, gbk, x, x_bf);
    }

    k_readout<<<BB, 256, 0, stream>>>(x, valid, g);
    k_mlp<<<BB, 128, 0, stream>>>(g, w0, b0, w1, b1, w2, b2, w3, b3, out);
}